// Round 1
// baseline (388.605 us; speedup 1.0000x reference)
//
#include <hip/hip_runtime.h>
#include <math.h>

#define B_  32
#define F_  10
#define N_  512
#define E_  8192
#define T_  16384      /* B_*N_ total nodes */
#define EB_ 262144     /* B_*E_ batched edges */
#define ET_ 278528     /* EB_+T_ edges incl self-loops */
#define HC_ 512
#define C_  256

// ---------------- edge decode (batched edges then self-loops) ----------------
__device__ __forceinline__ void decode_edge(int j, const int* __restrict__ esrc,
                                            const int* __restrict__ edst,
                                            int& s, int& d) {
    if (j < EB_) {
        int b = j >> 13;           // j / E_
        int e = j & (E_ - 1);
        int base = b << 9;         // b * N_
        s = esrc[e] + base;
        d = edst[e] + base;
    } else {
        s = d = j - EB_;
    }
}

// ---------------- CSR build ----------------
__global__ void hist_kernel(const int* __restrict__ eidx, int* __restrict__ cnt) {
    int j = blockIdx.x * 256 + threadIdx.x;
    if (j >= ET_) return;
    int s, d;
    decode_edge(j, eidx, eidx + E_, s, d);
    atomicAdd(&cnt[d], 1);
}

__global__ void scan_kernel(int* __restrict__ cnt /*in: counts, out: cursor*/,
                            int* __restrict__ off) {
    __shared__ int lds[1024];
    __shared__ int carry;
    int tid = threadIdx.x;
    if (tid == 0) carry = 0;
    __syncthreads();
    for (int base = 0; base < T_; base += 1024) {
        int v = cnt[base + tid];
        lds[tid] = v;
        __syncthreads();
        for (int d = 1; d < 1024; d <<= 1) {
            int add = (tid >= d) ? lds[tid - d] : 0;
            __syncthreads();
            lds[tid] += add;
            __syncthreads();
        }
        int incl = lds[tid];
        int c = carry;
        int excl = c + incl - v;
        off[base + tid] = excl;
        __syncthreads();
        if (tid == 1023) carry = c + incl;
        __syncthreads();
        cnt[base + tid] = excl;   // cursor copy (aliases counts buffer)
    }
    if (tid == 0) off[T_] = ET_;
}

__global__ void scatter_kernel(const int* __restrict__ eidx, int* __restrict__ cursor,
                               int* __restrict__ csr) {
    int j = blockIdx.x * 256 + threadIdx.x;
    if (j >= ET_) return;
    int s, d;
    decode_edge(j, eidx, eidx + E_, s, d);
    int pos = atomicAdd(&cursor[d], 1);
    csr[pos] = s;
}

// ---------------- layer 1 GEMM (K=10) + attention coefficients ----------------
__global__ __launch_bounds__(256) void gemm1_kernel(
    const float* __restrict__ X, const float* __restrict__ W1,
    const float* __restrict__ a_s, const float* __restrict__ a_d,
    float* __restrict__ Hout, float* __restrict__ als, float* __restrict__ ald) {
    int i = blockIdx.x, tid = threadIdx.x;
    __shared__ float xs[16];
    __shared__ float4 red[256];
    if (tid < F_) xs[tid] = X[i * F_ + tid];
    __syncthreads();
    float h0 = 0.f, h1 = 0.f;
#pragma unroll
    for (int k = 0; k < F_; ++k) {
        float xv = xs[k];
        h0 = fmaf(xv, W1[k * HC_ + tid], h0);
        h1 = fmaf(xv, W1[k * HC_ + C_ + tid], h1);
    }
    Hout[(size_t)i * HC_ + tid] = h0;
    Hout[(size_t)i * HC_ + C_ + tid] = h1;
    float4 p;
    p.x = h0 * a_s[tid];
    p.y = h1 * a_s[C_ + tid];
    p.z = h0 * a_d[tid];
    p.w = h1 * a_d[C_ + tid];
    red[tid] = p;
    __syncthreads();
    for (int s = 128; s > 0; s >>= 1) {
        if (tid < s) {
            float4 q = red[tid + s];
            float4 r = red[tid];
            r.x += q.x; r.y += q.y; r.z += q.z; r.w += q.w;
            red[tid] = r;
        }
        __syncthreads();
    }
    if (tid == 0) {
        als[i * 2 + 0] = red[0].x;
        als[i * 2 + 1] = red[0].y;
        ald[i * 2 + 0] = red[0].z;
        ald[i * 2 + 1] = red[0].w;
    }
}

// ---------------- attention coefficients for layer 2 (from H2) ----------------
__global__ __launch_bounds__(256) void al2_kernel(
    const float* __restrict__ H, const float* __restrict__ a_s,
    const float* __restrict__ a_d, float* __restrict__ als, float* __restrict__ ald) {
    int i = blockIdx.x, tid = threadIdx.x;
    __shared__ float4 red[256];
    float h0 = H[(size_t)i * HC_ + tid];
    float h1 = H[(size_t)i * HC_ + C_ + tid];
    float4 p;
    p.x = h0 * a_s[tid];
    p.y = h1 * a_s[C_ + tid];
    p.z = h0 * a_d[tid];
    p.w = h1 * a_d[C_ + tid];
    red[tid] = p;
    __syncthreads();
    for (int s = 128; s > 0; s >>= 1) {
        if (tid < s) {
            float4 q = red[tid + s];
            float4 r = red[tid];
            r.x += q.x; r.y += q.y; r.z += q.z; r.w += q.w;
            red[tid] = r;
        }
        __syncthreads();
    }
    if (tid == 0) {
        als[i * 2 + 0] = red[0].x;
        als[i * 2 + 1] = red[0].y;
        ald[i * 2 + 0] = red[0].z;
        ald[i * 2 + 1] = red[0].w;
    }
}

// ---------------- GAT aggregation: segment softmax + weighted gather ----------------
__global__ __launch_bounds__(256) void agg_kernel(
    const float* __restrict__ Hin, const float* __restrict__ als,
    const float* __restrict__ ald, const int* __restrict__ off,
    const int* __restrict__ csr, const float* __restrict__ bias,
    float* __restrict__ Xout) {
    int dst = blockIdx.x, tid = threadIdx.x;
    int beg = off[dst], end = off[dst + 1];
    float ad0 = ald[dst * 2], ad1 = ald[dst * 2 + 1];
    __shared__ float2 red[256];

    // pass 1: segment max
    float m0 = -1e30f, m1 = -1e30f;
    for (int k = beg + tid; k < end; k += 256) {
        int s = csr[k];
        float e0 = als[s * 2] + ad0;     e0 = e0 > 0.f ? e0 : 0.2f * e0;
        float e1 = als[s * 2 + 1] + ad1; e1 = e1 > 0.f ? e1 : 0.2f * e1;
        m0 = fmaxf(m0, e0);
        m1 = fmaxf(m1, e1);
    }
    red[tid] = make_float2(m0, m1);
    __syncthreads();
    for (int s = 128; s > 0; s >>= 1) {
        if (tid < s) {
            red[tid].x = fmaxf(red[tid].x, red[tid + s].x);
            red[tid].y = fmaxf(red[tid].y, red[tid + s].y);
        }
        __syncthreads();
    }
    m0 = red[0].x; m1 = red[0].y;
    __syncthreads();

    // pass 2: denom
    float d0 = 0.f, d1 = 0.f;
    for (int k = beg + tid; k < end; k += 256) {
        int s = csr[k];
        float e0 = als[s * 2] + ad0;     e0 = e0 > 0.f ? e0 : 0.2f * e0;
        float e1 = als[s * 2 + 1] + ad1; e1 = e1 > 0.f ? e1 : 0.2f * e1;
        d0 += expf(e0 - m0);
        d1 += expf(e1 - m1);
    }
    red[tid] = make_float2(d0, d1);
    __syncthreads();
    for (int s = 128; s > 0; s >>= 1) {
        if (tid < s) {
            red[tid].x += red[tid + s].x;
            red[tid].y += red[tid + s].y;
        }
        __syncthreads();
    }
    float inv0 = 1.f / (red[0].x + 1e-16f);
    float inv1 = 1.f / (red[0].y + 1e-16f);
    __syncthreads();

    // pass 3: weighted gather
    float acc0 = 0.f, acc1 = 0.f;
    for (int k = beg; k < end; ++k) {
        int s = csr[k];
        float e0 = als[s * 2] + ad0;     e0 = e0 > 0.f ? e0 : 0.2f * e0;
        float e1 = als[s * 2 + 1] + ad1; e1 = e1 > 0.f ? e1 : 0.2f * e1;
        float w0 = expf(e0 - m0) * inv0;
        float w1 = expf(e1 - m1) * inv1;
        acc0 = fmaf(w0, Hin[(size_t)s * HC_ + tid], acc0);
        acc1 = fmaf(w1, Hin[(size_t)s * HC_ + C_ + tid], acc1);
    }
    Xout[(size_t)dst * HC_ + tid] = acc0 + bias[tid];
    Xout[(size_t)dst * HC_ + C_ + tid] = acc1 + bias[C_ + tid];
}

// ---------------- layer 2 GEMM: [16384,512] @ [512,512], fp32 tiled ----------------
#define G2_BM 128
#define G2_BN 128
#define G2_BK 16

__global__ __launch_bounds__(256) void gemm2_kernel(
    const float* __restrict__ A, const float* __restrict__ Bm, float* __restrict__ Co) {
    __shared__ float As[G2_BK][G2_BM + 4];  // transposed: As[k][m], stride 132
    __shared__ float Bs[G2_BK][G2_BN];
    const int tid = threadIdx.x;
    const int tx = tid & 15;
    const int ty = tid >> 4;
    const int row0 = blockIdx.x * G2_BM;
    const int col0 = blockIdx.y * G2_BN;

    float acc[8][8];
#pragma unroll
    for (int i = 0; i < 8; i++)
#pragma unroll
        for (int j = 0; j < 8; j++) acc[i][j] = 0.f;

    for (int k0 = 0; k0 < HC_; k0 += G2_BK) {
#pragma unroll
        for (int l = 0; l < 2; ++l) {
            int idx = tid + l * 256;        // float4 units, 0..511
            int r = idx >> 2;               // 0..127
            int kq = (idx & 3) * 4;
            float4 v = *reinterpret_cast<const float4*>(
                &A[(size_t)(row0 + r) * HC_ + k0 + kq]);
            As[kq + 0][r] = v.x;
            As[kq + 1][r] = v.y;
            As[kq + 2][r] = v.z;
            As[kq + 3][r] = v.w;
        }
#pragma unroll
        for (int l = 0; l < 2; ++l) {
            int idx = tid + l * 256;
            int r = idx >> 5;               // 0..15
            int cq = (idx & 31) * 4;
            *reinterpret_cast<float4*>(&Bs[r][cq]) =
                *reinterpret_cast<const float4*>(&Bm[(size_t)(k0 + r) * HC_ + col0 + cq]);
        }
        __syncthreads();
#pragma unroll
        for (int kk = 0; kk < G2_BK; ++kk) {
            float a[8], b[8];
            *(float4*)&a[0] = *(float4*)&As[kk][ty * 8];
            *(float4*)&a[4] = *(float4*)&As[kk][ty * 8 + 4];
            *(float4*)&b[0] = *(float4*)&Bs[kk][tx * 8];
            *(float4*)&b[4] = *(float4*)&Bs[kk][tx * 8 + 4];
#pragma unroll
            for (int i = 0; i < 8; i++)
#pragma unroll
                for (int j = 0; j < 8; j++) acc[i][j] = fmaf(a[i], b[j], acc[i][j]);
        }
        __syncthreads();
    }
#pragma unroll
    for (int i = 0; i < 8; i++) {
        size_t r = (size_t)(row0 + ty * 8 + i) * HC_ + col0 + tx * 8;
#pragma unroll
        for (int j = 0; j < 8; j += 4)
            *reinterpret_cast<float4*>(&Co[r + j]) = *(float4*)&acc[i][j];
    }
}

// ---------------- final FC + BatchNorm(eval) + ReLU ----------------
__global__ __launch_bounds__(256) void fc_kernel(
    const float* __restrict__ X, const float* __restrict__ Wfc,
    const float* __restrict__ bfc, const float* __restrict__ gamma,
    const float* __restrict__ beta, float* __restrict__ out) {
    int i = blockIdx.x, tid = threadIdx.x;
    __shared__ float red[256];
    float v = X[(size_t)i * HC_ + tid] * Wfc[tid] +
              X[(size_t)i * HC_ + C_ + tid] * Wfc[C_ + tid];
    red[tid] = v;
    __syncthreads();
    for (int s = 128; s > 0; s >>= 1) {
        if (tid < s) red[tid] += red[tid + s];
        __syncthreads();
    }
    if (tid == 0) {
        float y = red[0] + bfc[0];
        y = y * (gamma[0] / sqrtf(1.f + 1e-5f)) + beta[0];
        out[i] = y > 0.f ? y : 0.f;
    }
}

// ---------------- launcher ----------------
extern "C" void kernel_launch(void* const* d_in, const int* in_sizes, int n_in,
                              void* d_out, int out_size, void* d_ws, size_t ws_size,
                              hipStream_t stream) {
    const float* data  = (const float*)d_in[0];
    const int*   eidx  = (const int*)d_in[1];
    const float* W1    = (const float*)d_in[2];
    const float* as1   = (const float*)d_in[3];
    const float* ad1   = (const float*)d_in[4];
    const float* b1    = (const float*)d_in[5];
    const float* W2    = (const float*)d_in[6];
    const float* as2   = (const float*)d_in[7];
    const float* ad2   = (const float*)d_in[8];
    const float* b2    = (const float*)d_in[9];
    const float* Wfc   = (const float*)d_in[10];
    const float* bfc   = (const float*)d_in[11];
    const float* gamma = (const float*)d_in[12];
    const float* beta  = (const float*)d_in[13];
    float* out = (float*)d_out;

    char* base = (char*)d_ws;
    size_t o = 0;
    auto take = [&](size_t bytes) {
        char* p = base + o;
        o = (o + bytes + 255) & ~(size_t)255;
        return p;
    };
    int*   cnt  = (int*)take((size_t)T_ * 4);        // counts -> cursor
    int*   off  = (int*)take((size_t)(T_ + 1) * 4);
    int*   csr  = (int*)take((size_t)ET_ * 4);
    float* als1 = (float*)take((size_t)T_ * 2 * 4);
    float* ald1 = (float*)take((size_t)T_ * 2 * 4);
    float* als2 = (float*)take((size_t)T_ * 2 * 4);
    float* ald2 = (float*)take((size_t)T_ * 2 * 4);
    float* hA   = (float*)take((size_t)T_ * HC_ * 4);  // h1, then h2
    float* hB   = (float*)take((size_t)T_ * HC_ * 4);  // x1, then x2

    const int egrid = (ET_ + 255) / 256;

    hipMemsetAsync(cnt, 0, (size_t)T_ * 4, stream);
    hist_kernel<<<egrid, 256, 0, stream>>>(eidx, cnt);
    scan_kernel<<<1, 1024, 0, stream>>>(cnt, off);
    scatter_kernel<<<egrid, 256, 0, stream>>>(eidx, cnt, csr);

    gemm1_kernel<<<T_, 256, 0, stream>>>(data, W1, as1, ad1, hA, als1, ald1);
    agg_kernel<<<T_, 256, 0, stream>>>(hA, als1, ald1, off, csr, b1, hB);

    gemm2_kernel<<<dim3(T_ / G2_BM, HC_ / G2_BN), 256, 0, stream>>>(hB, W2, hA);
    al2_kernel<<<T_, 256, 0, stream>>>(hA, as2, ad2, als2, ald2);
    agg_kernel<<<T_, 256, 0, stream>>>(hA, als2, ald2, off, csr, b2, hB);

    fc_kernel<<<T_, 256, 0, stream>>>(hB, Wfc, bfc, gamma, beta, out);
}

// Round 5
// 193.633 us; speedup vs baseline: 2.0069x; 2.0069x over previous
//
#include <hip/hip_runtime.h>
#include <math.h>

#define B_  32
#define F_  10
#define N_  512
#define E_  8192
#define T_  16384      /* B_*N_ total nodes */
#define EB_ 262144     /* B_*E_ batched edges */
#define ET_ 278528     /* EB_+T_ edges incl self-loops */
#define HC_ 512
#define C_  256

typedef __attribute__((ext_vector_type(8))) short bf16x8;
typedef __attribute__((ext_vector_type(4))) float f32x4;

__device__ __forceinline__ unsigned short f2bf(float f) {
    unsigned int u = __float_as_uint(f);
    u = (u + 0x7fffu + ((u >> 16) & 1u)) >> 16;
    return (unsigned short)u;
}
__device__ __forceinline__ float bf2f(unsigned short b) {
    return __uint_as_float(((unsigned int)b) << 16);
}
__device__ __forceinline__ float dot4(f32x4 a, f32x4 b) {
    f32x4 m = a * b;
    return m[0] + m[1] + m[2] + m[3];
}
__device__ __forceinline__ unsigned int pack2(unsigned short a, unsigned short b) {
    return (unsigned int)a | ((unsigned int)b << 16);
}

// batch→XCD swizzle: XCD x handles batches 4x..4x+3 (1MB h rows per batch → L2)
__device__ __forceinline__ int node_map(int bid, int wid) {
    int x = bid & 7;
    int rest = bid >> 3;          // 0..511
    int batch = x * 4 + (rest >> 7);
    int within = rest & 127;
    return batch * 512 + within * 4 + wid;
}

// ---------------- edge decode (batched edges then self-loops) ----------------
__device__ __forceinline__ void decode_edge(int j, const int* __restrict__ esrc,
                                            const int* __restrict__ edst,
                                            int& s, int& d) {
    if (j < EB_) {
        int b = j >> 13;
        int e = j & (E_ - 1);
        int base = b << 9;
        s = esrc[e] + base;
        d = edst[e] + base;
    } else {
        s = d = j - EB_;
    }
}

// ---------------- CSR build ----------------
__global__ void hist_kernel(const int* __restrict__ eidx, int* __restrict__ cnt) {
    int j = blockIdx.x * 256 + threadIdx.x;
    if (j >= ET_) return;
    int s, d;
    decode_edge(j, eidx, eidx + E_, s, d);
    atomicAdd(&cnt[d], 1);
}

__global__ __launch_bounds__(1024) void scan_kernel(int* __restrict__ cnt,
                                                    int* __restrict__ off) {
    __shared__ int lds[1024];
    int tid = threadIdx.x;
    int v[16], run[16];
    const int4* p = (const int4*)&cnt[tid * 16];
#pragma unroll
    for (int q = 0; q < 4; ++q) {
        int4 t = p[q];
        v[q * 4 + 0] = t.x; v[q * 4 + 1] = t.y; v[q * 4 + 2] = t.z; v[q * 4 + 3] = t.w;
    }
    int s = 0;
#pragma unroll
    for (int i = 0; i < 16; ++i) { run[i] = s; s += v[i]; }
    lds[tid] = s;
    __syncthreads();
    int inc = s;
    for (int d = 1; d < 1024; d <<= 1) {
        int add = (tid >= d) ? lds[tid - d] : 0;
        __syncthreads();
        lds[tid] += add;
        __syncthreads();
    }
    int base = lds[tid] - inc;
#pragma unroll
    for (int i = 0; i < 16; ++i) {
        int e = base + run[i];
        off[tid * 16 + i] = e;
        cnt[tid * 16 + i] = e;   // cursor copy for scatter
    }
    if (tid == 1023) off[T_] = ET_;
}

__global__ void scatter_kernel(const int* __restrict__ eidx, int* __restrict__ cursor,
                               int* __restrict__ csr) {
    int j = blockIdx.x * 256 + threadIdx.x;
    if (j >= ET_) return;
    int s, d;
    decode_edge(j, eidx, eidx + E_, s, d);
    int pos = atomicAdd(&cursor[d], 1);
    csr[pos] = s;
}

// ---------------- layer 1 GEMM (K=10) + attention coefficients, wave/node ----
__global__ __launch_bounds__(256) void gemm1_kernel(
    const float* __restrict__ X, const float* __restrict__ W1,
    const float* __restrict__ a_s, const float* __restrict__ a_d,
    float* __restrict__ H, float* __restrict__ als, float* __restrict__ ald) {
    int tid = threadIdx.x, lane = tid & 63, wid = tid >> 6;
    int node = node_map(blockIdx.x, wid);
    int col = lane * 8;
    float x[F_];
    const float* xp = X + (size_t)node * F_;
#pragma unroll
    for (int k = 0; k < F_; ++k) x[k] = xp[k];
    f32x4 h0 = {0.f, 0.f, 0.f, 0.f}, h1 = h0;
#pragma unroll
    for (int k = 0; k < F_; ++k) {
        f32x4 w0 = *(const f32x4*)&W1[k * HC_ + col];
        f32x4 w1 = *(const f32x4*)&W1[k * HC_ + col + 4];
        h0 += x[k] * w0;
        h1 += x[k] * w1;
    }
    *(f32x4*)&H[(size_t)node * HC_ + col] = h0;
    *(f32x4*)&H[(size_t)node * HC_ + col + 4] = h1;
    float ps = dot4(h0, *(const f32x4*)&a_s[col]) + dot4(h1, *(const f32x4*)&a_s[col + 4]);
    float pd = dot4(h0, *(const f32x4*)&a_d[col]) + dot4(h1, *(const f32x4*)&a_d[col + 4]);
#pragma unroll
    for (int m = 1; m <= 16; m <<= 1) {
        ps += __shfl_xor(ps, m);
        pd += __shfl_xor(pd, m);
    }
    if (lane == 0)  { als[node * 2 + 0] = ps; ald[node * 2 + 0] = pd; }
    if (lane == 32) { als[node * 2 + 1] = ps; ald[node * 2 + 1] = pd; }
}

// ---------------- attention coefficients for layer 2 (from H2), wave/node ----
__global__ __launch_bounds__(256) void al2_kernel(
    const float* __restrict__ H, const float* __restrict__ a_s,
    const float* __restrict__ a_d, float* __restrict__ als, float* __restrict__ ald) {
    int tid = threadIdx.x, lane = tid & 63, wid = tid >> 6;
    int node = node_map(blockIdx.x, wid);
    int col = lane * 8;
    f32x4 h0 = *(const f32x4*)&H[(size_t)node * HC_ + col];
    f32x4 h1 = *(const f32x4*)&H[(size_t)node * HC_ + col + 4];
    float ps = dot4(h0, *(const f32x4*)&a_s[col]) + dot4(h1, *(const f32x4*)&a_s[col + 4]);
    float pd = dot4(h0, *(const f32x4*)&a_d[col]) + dot4(h1, *(const f32x4*)&a_d[col + 4]);
#pragma unroll
    for (int m = 1; m <= 16; m <<= 1) {
        ps += __shfl_xor(ps, m);
        pd += __shfl_xor(pd, m);
    }
    if (lane == 0)  { als[node * 2 + 0] = ps; ald[node * 2 + 0] = pd; }
    if (lane == 32) { als[node * 2 + 1] = ps; ald[node * 2 + 1] = pd; }
}

// ---------------- GAT aggregation: wave per dst ----------------
// MODE 0: output hi/lo bf16 split (feeds MFMA gemm2). MODE 1: fused FC+BN+ReLU.
template <int MODE>
__global__ __launch_bounds__(256) void agg_kernel(
    const float* __restrict__ Hin, const float* __restrict__ als,
    const float* __restrict__ ald, const int* __restrict__ off,
    const int* __restrict__ csr, const float* __restrict__ bias,
    unsigned short* __restrict__ Ahi, unsigned short* __restrict__ Alo,
    const float* __restrict__ Wfc, const float* __restrict__ bfc,
    const float* __restrict__ gamma, const float* __restrict__ beta,
    float* __restrict__ out) {
    int tid = threadIdx.x, lane = tid & 63, wid = tid >> 6;
    int dst = node_map(blockIdx.x, wid);
    int beg = off[dst], end = off[dst + 1], deg = end - beg;
    float ad0 = ald[2 * dst], ad1 = ald[2 * dst + 1];
    int col = lane * 8;
    f32x4 A0 = {0.f, 0.f, 0.f, 0.f}, A1 = A0;

    if (deg <= 64) {
        float e0 = -1e30f, e1 = -1e30f;
        int sl = 0;
        if (lane < deg) {
            sl = csr[beg + lane];
            float a0 = als[2 * sl], a1 = als[2 * sl + 1];
            e0 = a0 + ad0; e0 = e0 > 0.f ? e0 : 0.2f * e0;
            e1 = a1 + ad1; e1 = e1 > 0.f ? e1 : 0.2f * e1;
        }
        float m0 = e0, m1 = e1;
#pragma unroll
        for (int m = 1; m < 64; m <<= 1) {
            m0 = fmaxf(m0, __shfl_xor(m0, m));
            m1 = fmaxf(m1, __shfl_xor(m1, m));
        }
        float x0 = (lane < deg) ? expf(e0 - m0) : 0.f;
        float x1 = (lane < deg) ? expf(e1 - m1) : 0.f;
        float d0 = x0, d1 = x1;
#pragma unroll
        for (int m = 1; m < 64; m <<= 1) {
            d0 += __shfl_xor(d0, m);
            d1 += __shfl_xor(d1, m);
        }
        float w0l = x0 / (d0 + 1e-16f);
        float w1l = x1 / (d1 + 1e-16f);
        for (int e = 0; e < deg; ++e) {
            int s = __shfl(sl, e);
            // CONVERGENT shuffles (ternary around __shfl is UB under divergence:
            // bpermute from exec-masked-off source lanes reads undefined/zero).
            float wa = __shfl(w0l, e);
            float wb = __shfl(w1l, e);
            float w = (lane < 32) ? wa : wb;
            const f32x4* p = (const f32x4*)(Hin + (size_t)s * HC_ + col);
            A0 += w * p[0];
            A1 += w * p[1];
        }
    } else {
        float m0 = -1e30f, m1 = -1e30f;
        for (int k = beg + lane; k < end; k += 64) {
            int s = csr[k];
            float e0 = als[2 * s] + ad0; e0 = e0 > 0.f ? e0 : 0.2f * e0;
            float e1 = als[2 * s + 1] + ad1; e1 = e1 > 0.f ? e1 : 0.2f * e1;
            m0 = fmaxf(m0, e0);
            m1 = fmaxf(m1, e1);
        }
#pragma unroll
        for (int m = 1; m < 64; m <<= 1) {
            m0 = fmaxf(m0, __shfl_xor(m0, m));
            m1 = fmaxf(m1, __shfl_xor(m1, m));
        }
        float d0 = 0.f, d1 = 0.f;
        for (int k = beg + lane; k < end; k += 64) {
            int s = csr[k];
            float e0 = als[2 * s] + ad0; e0 = e0 > 0.f ? e0 : 0.2f * e0;
            float e1 = als[2 * s + 1] + ad1; e1 = e1 > 0.f ? e1 : 0.2f * e1;
            d0 += expf(e0 - m0);
            d1 += expf(e1 - m1);
        }
#pragma unroll
        for (int m = 1; m < 64; m <<= 1) {
            d0 += __shfl_xor(d0, m);
            d1 += __shfl_xor(d1, m);
        }
        float inv0 = 1.f / (d0 + 1e-16f);
        float inv1 = 1.f / (d1 + 1e-16f);
        for (int k = beg; k < end; ++k) {
            int s = csr[k];
            float e0 = als[2 * s] + ad0; e0 = e0 > 0.f ? e0 : 0.2f * e0;
            float e1 = als[2 * s + 1] + ad1; e1 = e1 > 0.f ? e1 : 0.2f * e1;
            float w0 = expf(e0 - m0) * inv0;
            float w1 = expf(e1 - m1) * inv1;
            float w = (lane < 32) ? w0 : w1;
            const f32x4* p = (const f32x4*)(Hin + (size_t)s * HC_ + col);
            A0 += w * p[0];
            A1 += w * p[1];
        }
    }

    A0 += *(const f32x4*)&bias[col];
    A1 += *(const f32x4*)&bias[col + 4];

    if (MODE == 0) {
        unsigned short hi[8], lo[8];
#pragma unroll
        for (int j = 0; j < 4; ++j) {
            float v = A0[j];
            unsigned short hh = f2bf(v);
            hi[j] = hh; lo[j] = f2bf(v - bf2f(hh));
            v = A1[j];
            hh = f2bf(v);
            hi[4 + j] = hh; lo[4 + j] = f2bf(v - bf2f(hh));
        }
        uint4 uh, ul;
        uh.x = pack2(hi[0], hi[1]); uh.y = pack2(hi[2], hi[3]);
        uh.z = pack2(hi[4], hi[5]); uh.w = pack2(hi[6], hi[7]);
        ul.x = pack2(lo[0], lo[1]); ul.y = pack2(lo[2], lo[3]);
        ul.z = pack2(lo[4], lo[5]); ul.w = pack2(lo[6], lo[7]);
        *(uint4*)&Ahi[(size_t)dst * HC_ + col] = uh;
        *(uint4*)&Alo[(size_t)dst * HC_ + col] = ul;
    } else {
        float y = dot4(A0, *(const f32x4*)&Wfc[col]) +
                  dot4(A1, *(const f32x4*)&Wfc[col + 4]);
#pragma unroll
        for (int m = 1; m < 64; m <<= 1) y += __shfl_xor(y, m);
        if (lane == 0) {
            y += bfc[0];
            y = y * (gamma[0] * rsqrtf(1.f + 1e-5f)) + beta[0];
            out[dst] = y > 0.f ? y : 0.f;
        }
    }
}

// ---------------- W2 transpose + hi/lo bf16 split ----------------
__global__ __launch_bounds__(256) void wt_kernel(const float* __restrict__ W2,
                                                 unsigned short* __restrict__ Bhi,
                                                 unsigned short* __restrict__ Blo) {
    __shared__ float t[32][33];
    int tx = threadIdx.x & 31, ty = threadIdx.x >> 5;
    int kb = blockIdx.x * 32, nb = blockIdx.y * 32;
#pragma unroll
    for (int r = ty; r < 32; r += 8)
        t[r][tx] = W2[(size_t)(kb + r) * HC_ + nb + tx];
    __syncthreads();
#pragma unroll
    for (int r = ty; r < 32; r += 8) {
        float v = t[tx][r];
        unsigned short h = f2bf(v);
        Bhi[(size_t)(nb + r) * HC_ + kb + tx] = h;
        Blo[(size_t)(nb + r) * HC_ + kb + tx] = f2bf(v - bf2f(h));
    }
}

// ---------------- layer 2 GEMM: bf16x3 MFMA, 128x128 tile, XOR-swizzled LDS --
__global__ __launch_bounds__(256, 2) void gemm2_kernel(
    const unsigned short* __restrict__ Ahi, const unsigned short* __restrict__ Alo,
    const unsigned short* __restrict__ Bhi, const unsigned short* __restrict__ Blo,
    float* __restrict__ C) {
    __shared__ __align__(16) unsigned short smem[4 * 128 * 64];
    char* sA0 = (char*)smem;
    char* sA1 = sA0 + 16384;
    char* sB0 = sA1 + 16384;
    char* sB1 = sB0 + 16384;
    const int tid = threadIdx.x, lane = tid & 63, wid = tid >> 6;
    const int wr = wid >> 1, wc = wid & 1;
    const int bid = blockIdx.x;
    const int g = (bid & 7) * 64 + (bid >> 3);   // XCD swizzle: 16 row-panels/XCD
    const int row0 = (g >> 2) * 128, col0 = (g & 3) * 128;
    const int lr = lane & 15, lk = lane >> 4;
    const int x7 = lr & 7;

    f32x4 acc[4][4] = {};

    int wb[4];
    size_t ga[4], gb[4];
#pragma unroll
    for (int l = 0; l < 4; ++l) {
        int chunk = tid + l * 256;
        int r = chunk >> 3, c = chunk & 7;
        wb[l] = r * 128 + ((c ^ (r & 7)) << 4);
        ga[l] = (size_t)(row0 + r) * 64 + c;
        gb[l] = (size_t)(col0 + r) * 64 + c;
    }
    int rbA[4], rbB[4];
#pragma unroll
    for (int m = 0; m < 4; ++m) {
        rbA[m] = (wr * 64 + m * 16 + lr) * 128;
        rbB[m] = (wc * 64 + m * 16 + lr) * 128;
    }

    for (int kt = 0; kt < HC_; kt += 64) {
        uint4 va[4], vA[4], vb[4], vB[4];
        int k8 = kt >> 3;
#pragma unroll
        for (int l = 0; l < 4; ++l) {
            va[l] = ((const uint4*)Ahi)[ga[l] + k8];
            vA[l] = ((const uint4*)Alo)[ga[l] + k8];
            vb[l] = ((const uint4*)Bhi)[gb[l] + k8];
            vB[l] = ((const uint4*)Blo)[gb[l] + k8];
        }
        __syncthreads();
#pragma unroll
        for (int l = 0; l < 4; ++l) {
            *(uint4*)(sA0 + wb[l]) = va[l];
            *(uint4*)(sA1 + wb[l]) = vA[l];
            *(uint4*)(sB0 + wb[l]) = vb[l];
            *(uint4*)(sB1 + wb[l]) = vB[l];
        }
        __syncthreads();
#pragma unroll
        for (int kk = 0; kk < 2; ++kk) {
            int cx = ((kk * 4 + lk) ^ x7) << 4;
            bf16x8 ah[4], al[4], bh[4], bl[4];
#pragma unroll
            for (int m = 0; m < 4; ++m) {
                ah[m] = *(const bf16x8*)(sA0 + rbA[m] + cx);
                al[m] = *(const bf16x8*)(sA1 + rbA[m] + cx);
                bh[m] = *(const bf16x8*)(sB0 + rbB[m] + cx);
                bl[m] = *(const bf16x8*)(sB1 + rbB[m] + cx);
            }
#pragma unroll
            for (int m = 0; m < 4; ++m)
#pragma unroll
                for (int n = 0; n < 4; ++n) {
                    acc[m][n] = __builtin_amdgcn_mfma_f32_16x16x32_bf16(ah[m], bh[n], acc[m][n], 0, 0, 0);
                    acc[m][n] = __builtin_amdgcn_mfma_f32_16x16x32_bf16(ah[m], bl[n], acc[m][n], 0, 0, 0);
                    acc[m][n] = __builtin_amdgcn_mfma_f32_16x16x32_bf16(al[m], bh[n], acc[m][n], 0, 0, 0);
                }
        }
        __syncthreads();
    }
#pragma unroll
    for (int m = 0; m < 4; ++m) {
        int row = row0 + wr * 64 + m * 16 + lk * 4;
#pragma unroll
        for (int i = 0; i < 4; ++i) {
            float* cp = C + (size_t)(row + i) * HC_ + col0 + wc * 64 + lr;
#pragma unroll
            for (int n = 0; n < 4; ++n) cp[n * 16] = acc[m][n][i];
        }
    }
}

// ---------------- launcher ----------------
extern "C" void kernel_launch(void* const* d_in, const int* in_sizes, int n_in,
                              void* d_out, int out_size, void* d_ws, size_t ws_size,
                              hipStream_t stream) {
    const float* data  = (const float*)d_in[0];
    const int*   eidx  = (const int*)d_in[1];
    const float* W1    = (const float*)d_in[2];
    const float* as1   = (const float*)d_in[3];
    const float* ad1   = (const float*)d_in[4];
    const float* b1    = (const float*)d_in[5];
    const float* W2    = (const float*)d_in[6];
    const float* as2   = (const float*)d_in[7];
    const float* ad2   = (const float*)d_in[8];
    const float* b2    = (const float*)d_in[9];
    const float* Wfc   = (const float*)d_in[10];
    const float* bfc   = (const float*)d_in[11];
    const float* gamma = (const float*)d_in[12];
    const float* beta  = (const float*)d_in[13];
    float* out = (float*)d_out;

    char* base = (char*)d_ws;
    size_t o = 0;
    auto take = [&](size_t bytes) {
        char* p = base + o;
        o = (o + bytes + 255) & ~(size_t)255;
        return p;
    };
    int*   cnt  = (int*)take((size_t)T_ * 4);
    int*   off  = (int*)take((size_t)(T_ + 1) * 4);
    int*   csr  = (int*)take((size_t)ET_ * 4);
    float* als1 = (float*)take((size_t)T_ * 2 * 4);
    float* ald1 = (float*)take((size_t)T_ * 2 * 4);
    float* als2 = (float*)take((size_t)T_ * 2 * 4);
    float* ald2 = (float*)take((size_t)T_ * 2 * 4);
    float* h    = (float*)take((size_t)T_ * HC_ * 4);   // h1, later h2
    unsigned short* Ahi = (unsigned short*)take((size_t)T_ * HC_ * 2);
    unsigned short* Alo = (unsigned short*)take((size_t)T_ * HC_ * 2);
    unsigned short* Bhi = (unsigned short*)take((size_t)HC_ * HC_ * 2);
    unsigned short* Blo = (unsigned short*)take((size_t)HC_ * HC_ * 2);

    const int egrid = (ET_ + 255) / 256;

    hipMemsetAsync(cnt, 0, (size_t)T_ * 4, stream);
    hist_kernel<<<egrid, 256, 0, stream>>>(eidx, cnt);
    scan_kernel<<<1, 1024, 0, stream>>>(cnt, off);
    scatter_kernel<<<egrid, 256, 0, stream>>>(eidx, cnt, csr);
    wt_kernel<<<dim3(16, 16), 256, 0, stream>>>(W2, Bhi, Blo);

    gemm1_kernel<<<4096, 256, 0, stream>>>(data, W1, as1, ad1, h, als1, ald1);
    agg_kernel<0><<<4096, 256, 0, stream>>>(h, als1, ald1, off, csr, b1,
                                            Ahi, Alo, nullptr, nullptr, nullptr,
                                            nullptr, nullptr);
    gemm2_kernel<<<512, 256, 0, stream>>>(Ahi, Alo, Bhi, Blo, h);
    al2_kernel<<<4096, 256, 0, stream>>>(h, as2, ad2, als2, ald2);
    agg_kernel<1><<<4096, 256, 0, stream>>>(h, als2, ald2, off, csr, b2,
                                            nullptr, nullptr, Wfc, bfc, gamma,
                                            beta, out);
}

// Round 6
// 133.579 us; speedup vs baseline: 2.9092x; 1.4496x over previous
//
#include <hip/hip_runtime.h>
#include <math.h>

#define B_  32
#define F_  10
#define N_  512
#define E_  8192
#define T_  16384      /* B_*N_ total nodes */
#define EB_ 262144     /* B_*E_ batched edges */
#define ET_ 278528     /* EB_+T_ edges incl self-loops */
#define HC_ 512
#define C_  256

typedef __attribute__((ext_vector_type(8))) short bf16x8;
typedef __attribute__((ext_vector_type(4))) float f32x4;

__device__ __forceinline__ unsigned short f2bf(float f) {
    unsigned int u = __float_as_uint(f);
    u = (u + 0x7fffu + ((u >> 16) & 1u)) >> 16;
    return (unsigned short)u;
}
__device__ __forceinline__ float bf2f(unsigned short b) {
    return __uint_as_float(((unsigned int)b) << 16);
}
__device__ __forceinline__ float dot4(f32x4 a, f32x4 b) {
    f32x4 m = a * b;
    return m[0] + m[1] + m[2] + m[3];
}
__device__ __forceinline__ unsigned int pack2(unsigned short a, unsigned short b) {
    return (unsigned int)a | ((unsigned int)b << 16);
}
__device__ __forceinline__ void async_cp16(const void* g, void* l) {
    __builtin_amdgcn_global_load_lds(
        (const __attribute__((address_space(1))) unsigned int*)g,
        (__attribute__((address_space(3))) unsigned int*)l, 16, 0, 0);
}

// batch→XCD swizzle: XCD x handles batches 4x..4x+3 (1MB h rows per batch → L2)
__device__ __forceinline__ int node_map(int bid, int wid) {
    int x = bid & 7;
    int rest = bid >> 3;          // 0..511
    int batch = x * 4 + (rest >> 7);
    int within = rest & 127;
    return batch * 512 + within * 4 + wid;
}

// ---------------- edge decode (batched edges then self-loops) ----------------
__device__ __forceinline__ void decode_edge(int j, const int* __restrict__ esrc,
                                            const int* __restrict__ edst,
                                            int& s, int& d) {
    if (j < EB_) {
        int b = j >> 13;
        int e = j & (E_ - 1);
        int base = b << 9;
        s = esrc[e] + base;
        d = edst[e] + base;
    } else {
        s = d = j - EB_;
    }
}

// ---------------- CSR build ----------------
__global__ void hist_kernel(const int* __restrict__ eidx, int* __restrict__ cnt) {
    int j = blockIdx.x * 256 + threadIdx.x;
    if (j >= ET_) return;
    int s, d;
    decode_edge(j, eidx, eidx + E_, s, d);
    atomicAdd(&cnt[d], 1);
}

__global__ __launch_bounds__(1024) void scan_kernel(int* __restrict__ cnt,
                                                    int* __restrict__ off) {
    __shared__ int lds[1024];
    int tid = threadIdx.x;
    int v[16], run[16];
    const int4* p = (const int4*)&cnt[tid * 16];
#pragma unroll
    for (int q = 0; q < 4; ++q) {
        int4 t = p[q];
        v[q * 4 + 0] = t.x; v[q * 4 + 1] = t.y; v[q * 4 + 2] = t.z; v[q * 4 + 3] = t.w;
    }
    int s = 0;
#pragma unroll
    for (int i = 0; i < 16; ++i) { run[i] = s; s += v[i]; }
    lds[tid] = s;
    __syncthreads();
    int inc = s;
    for (int d = 1; d < 1024; d <<= 1) {
        int add = (tid >= d) ? lds[tid - d] : 0;
        __syncthreads();
        lds[tid] += add;
        __syncthreads();
    }
    int base = lds[tid] - inc;
#pragma unroll
    for (int i = 0; i < 16; ++i) {
        int e = base + run[i];
        off[tid * 16 + i] = e;
        cnt[tid * 16 + i] = e;   // cursor copy for scatter
    }
    if (tid == 1023) off[T_] = ET_;
}

__global__ void scatter_kernel(const int* __restrict__ eidx, int* __restrict__ cursor,
                               int* __restrict__ csr) {
    int j = blockIdx.x * 256 + threadIdx.x;
    if (j >= ET_) return;
    int s, d;
    decode_edge(j, eidx, eidx + E_, s, d);
    int pos = atomicAdd(&cursor[d], 1);
    csr[pos] = s;
}

// ---------------- layer 1 GEMM (K=10) + attention coefficients, wave/node ----
__global__ __launch_bounds__(256) void gemm1_kernel(
    const float* __restrict__ X, const float* __restrict__ W1,
    const float* __restrict__ a_s, const float* __restrict__ a_d,
    float* __restrict__ H, float* __restrict__ als, float* __restrict__ ald) {
    int tid = threadIdx.x, lane = tid & 63, wid = tid >> 6;
    int node = node_map(blockIdx.x, wid);
    int col = lane * 8;
    float x[F_];
    const float* xp = X + (size_t)node * F_;
#pragma unroll
    for (int k = 0; k < F_; ++k) x[k] = xp[k];
    f32x4 h0 = {0.f, 0.f, 0.f, 0.f}, h1 = h0;
#pragma unroll
    for (int k = 0; k < F_; ++k) {
        f32x4 w0 = *(const f32x4*)&W1[k * HC_ + col];
        f32x4 w1 = *(const f32x4*)&W1[k * HC_ + col + 4];
        h0 += x[k] * w0;
        h1 += x[k] * w1;
    }
    *(f32x4*)&H[(size_t)node * HC_ + col] = h0;
    *(f32x4*)&H[(size_t)node * HC_ + col + 4] = h1;
    float ps = dot4(h0, *(const f32x4*)&a_s[col]) + dot4(h1, *(const f32x4*)&a_s[col + 4]);
    float pd = dot4(h0, *(const f32x4*)&a_d[col]) + dot4(h1, *(const f32x4*)&a_d[col + 4]);
#pragma unroll
    for (int m = 1; m <= 16; m <<= 1) {
        ps += __shfl_xor(ps, m);
        pd += __shfl_xor(pd, m);
    }
    if (lane == 0)  { als[node * 2 + 0] = ps; ald[node * 2 + 0] = pd; }
    if (lane == 32) { als[node * 2 + 1] = ps; ald[node * 2 + 1] = pd; }
}

// ---------------- attention coefficients for layer 2 (from H2), wave/node ----
__global__ __launch_bounds__(256) void al2_kernel(
    const float* __restrict__ H, const float* __restrict__ a_s,
    const float* __restrict__ a_d, float* __restrict__ als, float* __restrict__ ald) {
    int tid = threadIdx.x, lane = tid & 63, wid = tid >> 6;
    int node = node_map(blockIdx.x, wid);
    int col = lane * 8;
    f32x4 h0 = *(const f32x4*)&H[(size_t)node * HC_ + col];
    f32x4 h1 = *(const f32x4*)&H[(size_t)node * HC_ + col + 4];
    float ps = dot4(h0, *(const f32x4*)&a_s[col]) + dot4(h1, *(const f32x4*)&a_s[col + 4]);
    float pd = dot4(h0, *(const f32x4*)&a_d[col]) + dot4(h1, *(const f32x4*)&a_d[col + 4]);
#pragma unroll
    for (int m = 1; m <= 16; m <<= 1) {
        ps += __shfl_xor(ps, m);
        pd += __shfl_xor(pd, m);
    }
    if (lane == 0)  { als[node * 2 + 0] = ps; ald[node * 2 + 0] = pd; }
    if (lane == 32) { als[node * 2 + 1] = ps; ald[node * 2 + 1] = pd; }
}

// ---------------- GAT aggregation: wave per dst ----------------
// MODE 0: output bf16 x1 (feeds MFMA gemm2). MODE 1: fused FC+BN+ReLU.
template <int MODE>
__global__ __launch_bounds__(256) void agg_kernel(
    const float* __restrict__ Hin, const float* __restrict__ als,
    const float* __restrict__ ald, const int* __restrict__ off,
    const int* __restrict__ csr, const float* __restrict__ bias,
    unsigned short* __restrict__ Ahi,
    const float* __restrict__ Wfc, const float* __restrict__ bfc,
    const float* __restrict__ gamma, const float* __restrict__ beta,
    float* __restrict__ out) {
    int tid = threadIdx.x, lane = tid & 63, wid = tid >> 6;
    int dst = node_map(blockIdx.x, wid);
    int beg = off[dst], end = off[dst + 1], deg = end - beg;
    float ad0 = ald[2 * dst], ad1 = ald[2 * dst + 1];
    int col = lane * 8;
    f32x4 A0 = {0.f, 0.f, 0.f, 0.f}, A1 = A0;

    if (deg <= 64) {
        float e0 = -1e30f, e1 = -1e30f;
        int sl = 0;
        if (lane < deg) {
            sl = csr[beg + lane];
            float a0 = als[2 * sl], a1 = als[2 * sl + 1];
            e0 = a0 + ad0; e0 = e0 > 0.f ? e0 : 0.2f * e0;
            e1 = a1 + ad1; e1 = e1 > 0.f ? e1 : 0.2f * e1;
        }
        float m0 = e0, m1 = e1;
#pragma unroll
        for (int m = 1; m < 64; m <<= 1) {
            m0 = fmaxf(m0, __shfl_xor(m0, m));
            m1 = fmaxf(m1, __shfl_xor(m1, m));
        }
        float x0 = (lane < deg) ? expf(e0 - m0) : 0.f;
        float x1 = (lane < deg) ? expf(e1 - m1) : 0.f;
        float d0 = x0, d1 = x1;
#pragma unroll
        for (int m = 1; m < 64; m <<= 1) {
            d0 += __shfl_xor(d0, m);
            d1 += __shfl_xor(d1, m);
        }
        float w0l = x0 / (d0 + 1e-16f);
        float w1l = x1 / (d1 + 1e-16f);
        for (int e = 0; e < deg; ++e) {
            int s = __shfl(sl, e);
            // CONVERGENT shuffles (ternary around __shfl is UB under divergence).
            float wa = __shfl(w0l, e);
            float wb = __shfl(w1l, e);
            float w = (lane < 32) ? wa : wb;
            const f32x4* p = (const f32x4*)(Hin + (size_t)s * HC_ + col);
            A0 += w * p[0];
            A1 += w * p[1];
        }
    } else {
        float m0 = -1e30f, m1 = -1e30f;
        for (int k = beg + lane; k < end; k += 64) {
            int s = csr[k];
            float e0 = als[2 * s] + ad0; e0 = e0 > 0.f ? e0 : 0.2f * e0;
            float e1 = als[2 * s + 1] + ad1; e1 = e1 > 0.f ? e1 : 0.2f * e1;
            m0 = fmaxf(m0, e0);
            m1 = fmaxf(m1, e1);
        }
#pragma unroll
        for (int m = 1; m < 64; m <<= 1) {
            m0 = fmaxf(m0, __shfl_xor(m0, m));
            m1 = fmaxf(m1, __shfl_xor(m1, m));
        }
        float d0 = 0.f, d1 = 0.f;
        for (int k = beg + lane; k < end; k += 64) {
            int s = csr[k];
            float e0 = als[2 * s] + ad0; e0 = e0 > 0.f ? e0 : 0.2f * e0;
            float e1 = als[2 * s + 1] + ad1; e1 = e1 > 0.f ? e1 : 0.2f * e1;
            d0 += expf(e0 - m0);
            d1 += expf(e1 - m1);
        }
#pragma unroll
        for (int m = 1; m < 64; m <<= 1) {
            d0 += __shfl_xor(d0, m);
            d1 += __shfl_xor(d1, m);
        }
        float inv0 = 1.f / (d0 + 1e-16f);
        float inv1 = 1.f / (d1 + 1e-16f);
        for (int k = beg; k < end; ++k) {
            int s = csr[k];
            float e0 = als[2 * s] + ad0; e0 = e0 > 0.f ? e0 : 0.2f * e0;
            float e1 = als[2 * s + 1] + ad1; e1 = e1 > 0.f ? e1 : 0.2f * e1;
            float w0 = expf(e0 - m0) * inv0;
            float w1 = expf(e1 - m1) * inv1;
            float w = (lane < 32) ? w0 : w1;
            const f32x4* p = (const f32x4*)(Hin + (size_t)s * HC_ + col);
            A0 += w * p[0];
            A1 += w * p[1];
        }
    }

    A0 += *(const f32x4*)&bias[col];
    A1 += *(const f32x4*)&bias[col + 4];

    if (MODE == 0) {
        uint4 uh;
        uh.x = pack2(f2bf(A0[0]), f2bf(A0[1]));
        uh.y = pack2(f2bf(A0[2]), f2bf(A0[3]));
        uh.z = pack2(f2bf(A1[0]), f2bf(A1[1]));
        uh.w = pack2(f2bf(A1[2]), f2bf(A1[3]));
        *(uint4*)&Ahi[(size_t)dst * HC_ + col] = uh;
    } else {
        float y = dot4(A0, *(const f32x4*)&Wfc[col]) +
                  dot4(A1, *(const f32x4*)&Wfc[col + 4]);
#pragma unroll
        for (int m = 1; m < 64; m <<= 1) y += __shfl_xor(y, m);
        if (lane == 0) {
            y += bfc[0];
            y = y * (gamma[0] * rsqrtf(1.f + 1e-5f)) + beta[0];
            out[dst] = y > 0.f ? y : 0.f;
        }
    }
}

// ---------------- W2 transpose + hi/lo bf16 split ----------------
__global__ __launch_bounds__(256) void wt_kernel(const float* __restrict__ W2,
                                                 unsigned short* __restrict__ Bhi,
                                                 unsigned short* __restrict__ Blo) {
    __shared__ float t[32][33];
    int tx = threadIdx.x & 31, ty = threadIdx.x >> 5;
    int kb = blockIdx.x * 32, nb = blockIdx.y * 32;
#pragma unroll
    for (int r = ty; r < 32; r += 8)
        t[r][tx] = W2[(size_t)(kb + r) * HC_ + nb + tx];
    __syncthreads();
#pragma unroll
    for (int r = ty; r < 32; r += 8) {
        float v = t[tx][r];
        unsigned short h = f2bf(v);
        Bhi[(size_t)(nb + r) * HC_ + kb + tx] = h;
        Blo[(size_t)(nb + r) * HC_ + kb + tx] = f2bf(v - bf2f(h));
    }
}

// ---------------- layer 2 GEMM: bf16x2 MFMA, 256x128 tile -------------------
// global_load_lds staging (swizzle on SOURCE addr, linear LDS dest, XOR read),
// 2-deep async pipeline: raw s_barrier + explicit vmcnt, 1 barrier per K-step.
// C = Ahi*(Bhi+Blo); dropped lo(A) term ~1.4e-4 rms on x2 (<< 1.4e-3 thr).
__global__ __launch_bounds__(512, 1) void gemm2_kernel(
    const unsigned short* __restrict__ Ahi,
    const unsigned short* __restrict__ Bhi, const unsigned short* __restrict__ Blo,
    float* __restrict__ C) {
    // per buf (64 KiB): A 256x64 bf16 @0, Bh 128x64 @32768, Bl 128x64 @49152
    __shared__ __align__(16) unsigned short smem[2 * 512 * 64];  // 128 KiB
    const int tid = threadIdx.x, lane = tid & 63, wid = tid >> 6;
    const int wr = wid >> 1, wc = wid & 1;
    const int g = (blockIdx.x & 7) * 32 + (blockIdx.x >> 3);  // XCD swizzle
    const int row0 = (g >> 2) * 256, col0 = (g & 3) * 128;
    const int lr = lane & 15, lk = lane >> 4;
    const int x7 = lr & 7;

    f32x4 acc[4][4] = {};

    // 8 chunk-loads/thread/K-step over [A:2048 | Bh:1024 | Bl:1024] 16B chunks.
    const char* gsrc[8];
    int loff[8];
#pragma unroll
    for (int l = 0; l < 8; ++l) {
        int i = tid + l * 512;
        if (i < 2048) {
            int r = i >> 3, c = i & 7;
            gsrc[l] = (const char*)(Ahi + (size_t)(row0 + r) * HC_ + ((c ^ (r & 7)) << 3));
            loff[l] = i << 4;
        } else if (i < 3072) {
            int j = i - 2048, r = j >> 3, c = j & 7;
            gsrc[l] = (const char*)(Bhi + (size_t)(col0 + r) * HC_ + ((c ^ (r & 7)) << 3));
            loff[l] = 32768 + (j << 4);
        } else {
            int j = i - 3072, r = j >> 3, c = j & 7;
            gsrc[l] = (const char*)(Blo + (size_t)(col0 + r) * HC_ + ((c ^ (r & 7)) << 3));
            loff[l] = 49152 + (j << 4);
        }
    }
    char* lds0 = (char*)smem;

    // prologue: stage kt=0 into buf0
#pragma unroll
    for (int l = 0; l < 8; ++l) async_cp16(gsrc[l], lds0 + loff[l]);
    asm volatile("s_waitcnt vmcnt(0)" ::: "memory");
    __builtin_amdgcn_s_barrier();

    int cur = 0;
    for (int kt = 0; kt < 8; ++kt) {
        if (kt < 7) {  // issue next tile's loads BEFORE compute (latency hides)
            char* dst = lds0 + ((cur ^ 1) << 16);
#pragma unroll
            for (int l = 0; l < 8; ++l)
                async_cp16(gsrc[l] + (size_t)(kt + 1) * 128, dst + loff[l]);
        }
        const char* base = lds0 + (cur << 16);
#pragma unroll
        for (int kk = 0; kk < 2; ++kk) {
            bf16x8 a[4], bh[4], bl[4];
            int cx = ((kk * 4 + lk) ^ x7) << 4;
#pragma unroll
            for (int m = 0; m < 4; ++m) {
                int ra = wr * 64 + m * 16 + lr;
                int rb = wc * 64 + m * 16 + lr;
                a[m]  = *(const bf16x8*)(base + ra * 128 + cx);
                bh[m] = *(const bf16x8*)(base + 32768 + rb * 128 + cx);
                bl[m] = *(const bf16x8*)(base + 49152 + rb * 128 + cx);
            }
#pragma unroll
            for (int m = 0; m < 4; ++m)
#pragma unroll
                for (int n = 0; n < 4; ++n) {
                    acc[m][n] = __builtin_amdgcn_mfma_f32_16x16x32_bf16(a[m], bh[n], acc[m][n], 0, 0, 0);
                    acc[m][n] = __builtin_amdgcn_mfma_f32_16x16x32_bf16(a[m], bl[n], acc[m][n], 0, 0, 0);
                }
        }
        asm volatile("s_waitcnt vmcnt(0)" ::: "memory");
        __builtin_amdgcn_s_barrier();
        cur ^= 1;
    }
#pragma unroll
    for (int m = 0; m < 4; ++m) {
        int row = row0 + wr * 64 + m * 16 + lk * 4;
#pragma unroll
        for (int i = 0; i < 4; ++i) {
            float* cp = C + (size_t)(row + i) * HC_ + col0 + wc * 64 + lr;
#pragma unroll
            for (int n = 0; n < 4; ++n) cp[n * 16] = acc[m][n][i];
        }
    }
}

// ---------------- launcher ----------------
extern "C" void kernel_launch(void* const* d_in, const int* in_sizes, int n_in,
                              void* d_out, int out_size, void* d_ws, size_t ws_size,
                              hipStream_t stream) {
    const float* data  = (const float*)d_in[0];
    const int*   eidx  = (const int*)d_in[1];
    const float* W1    = (const float*)d_in[2];
    const float* as1   = (const float*)d_in[3];
    const float* ad1   = (const float*)d_in[4];
    const float* b1    = (const float*)d_in[5];
    const float* W2    = (const float*)d_in[6];
    const float* as2   = (const float*)d_in[7];
    const float* ad2   = (const float*)d_in[8];
    const float* b2    = (const float*)d_in[9];
    const float* Wfc   = (const float*)d_in[10];
    const float* bfc   = (const float*)d_in[11];
    const float* gamma = (const float*)d_in[12];
    const float* beta  = (const float*)d_in[13];
    float* out = (float*)d_out;

    char* base = (char*)d_ws;
    size_t o = 0;
    auto take = [&](size_t bytes) {
        char* p = base + o;
        o = (o + bytes + 255) & ~(size_t)255;
        return p;
    };
    int*   cnt  = (int*)take((size_t)T_ * 4);
    int*   off  = (int*)take((size_t)(T_ + 1) * 4);
    int*   csr  = (int*)take((size_t)ET_ * 4);
    float* als1 = (float*)take((size_t)T_ * 2 * 4);
    float* ald1 = (float*)take((size_t)T_ * 2 * 4);
    float* als2 = (float*)take((size_t)T_ * 2 * 4);
    float* ald2 = (float*)take((size_t)T_ * 2 * 4);
    float* h    = (float*)take((size_t)T_ * HC_ * 4);   // h1, later h2
    unsigned short* Ahi = (unsigned short*)take((size_t)T_ * HC_ * 2);
    unsigned short* Bhi = (unsigned short*)take((size_t)HC_ * HC_ * 2);
    unsigned short* Blo = (unsigned short*)take((size_t)HC_ * HC_ * 2);

    const int egrid = (ET_ + 255) / 256;

    hipMemsetAsync(cnt, 0, (size_t)T_ * 4, stream);
    hist_kernel<<<egrid, 256, 0, stream>>>(eidx, cnt);
    scan_kernel<<<1, 1024, 0, stream>>>(cnt, off);
    scatter_kernel<<<egrid, 256, 0, stream>>>(eidx, cnt, csr);
    wt_kernel<<<dim3(16, 16), 256, 0, stream>>>(W2, Bhi, Blo);

    gemm1_kernel<<<4096, 256, 0, stream>>>(data, W1, as1, ad1, h, als1, ald1);
    agg_kernel<0><<<4096, 256, 0, stream>>>(h, als1, ald1, off, csr, b1,
                                            Ahi, nullptr, nullptr, nullptr,
                                            nullptr, nullptr);
    gemm2_kernel<<<256, 512, 0, stream>>>(Ahi, Bhi, Blo, h);
    al2_kernel<<<4096, 256, 0, stream>>>(h, as2, ad2, als2, ald2);
    agg_kernel<1><<<4096, 256, 0, stream>>>(h, als2, ald2, off, csr, b2,
                                            nullptr, Wfc, bfc, gamma,
                                            beta, out);
}

// Round 7
// 120.798 us; speedup vs baseline: 3.2170x; 1.1058x over previous
//
#include <hip/hip_runtime.h>
#include <math.h>

#define B_  32
#define F_  10
#define N_  512
#define E_  8192
#define T_  16384      /* B_*N_ total nodes */
#define EB_ 262144     /* B_*E_ batched edges */
#define ET_ 278528     /* EB_+T_ edges incl self-loops */
#define HC_ 512
#define C_  256

typedef __attribute__((ext_vector_type(8))) short bf16x8;
typedef __attribute__((ext_vector_type(4))) float f32x4;

__device__ __forceinline__ unsigned short f2bf(float f) {
    unsigned int u = __float_as_uint(f);
    u = (u + 0x7fffu + ((u >> 16) & 1u)) >> 16;
    return (unsigned short)u;
}
__device__ __forceinline__ float dot4(f32x4 a, f32x4 b) {
    f32x4 m = a * b;
    return m[0] + m[1] + m[2] + m[3];
}
__device__ __forceinline__ unsigned int pack2(unsigned short a, unsigned short b) {
    return (unsigned int)a | ((unsigned int)b << 16);
}
// expand packed 2x bf16 -> 2 floats (low: shift, high: mask — 2 VALU ops)
__device__ __forceinline__ void bf2x2(unsigned int u, float& f0, float& f1) {
    f0 = __uint_as_float(u << 16);
    f1 = __uint_as_float(u & 0xffff0000u);
}
__device__ __forceinline__ void async_cp16(const void* g, void* l) {
    __builtin_amdgcn_global_load_lds(
        (const __attribute__((address_space(1))) unsigned int*)g,
        (__attribute__((address_space(3))) unsigned int*)l, 16, 0, 0);
}

// batch→XCD swizzle: XCD x handles batches 4x..4x+3 (h rows per batch → L2)
__device__ __forceinline__ int node_map(int bid, int wid) {
    int x = bid & 7;
    int rest = bid >> 3;          // 0..511
    int batch = x * 4 + (rest >> 7);
    int within = rest & 127;
    return batch * 512 + within * 4 + wid;
}

// ---------------- edge decode (batched edges then self-loops) ----------------
__device__ __forceinline__ void decode_edge(int j, const int* __restrict__ esrc,
                                            const int* __restrict__ edst,
                                            int& s, int& d) {
    if (j < EB_) {
        int b = j >> 13;
        int e = j & (E_ - 1);
        int base = b << 9;
        s = esrc[e] + base;
        d = edst[e] + base;
    } else {
        s = d = j - EB_;
    }
}

// ---------------- CSR build ----------------
__global__ void hist_kernel(const int* __restrict__ eidx, int* __restrict__ cnt) {
    int j = blockIdx.x * 256 + threadIdx.x;
    if (j >= ET_) return;
    int s, d;
    decode_edge(j, eidx, eidx + E_, s, d);
    atomicAdd(&cnt[d], 1);
}

__global__ __launch_bounds__(1024) void scan_kernel(int* __restrict__ cnt,
                                                    int* __restrict__ off) {
    __shared__ int lds[1024];
    int tid = threadIdx.x;
    int v[16], run[16];
    const int4* p = (const int4*)&cnt[tid * 16];
#pragma unroll
    for (int q = 0; q < 4; ++q) {
        int4 t = p[q];
        v[q * 4 + 0] = t.x; v[q * 4 + 1] = t.y; v[q * 4 + 2] = t.z; v[q * 4 + 3] = t.w;
    }
    int s = 0;
#pragma unroll
    for (int i = 0; i < 16; ++i) { run[i] = s; s += v[i]; }
    lds[tid] = s;
    __syncthreads();
    int inc = s;
    for (int d = 1; d < 1024; d <<= 1) {
        int add = (tid >= d) ? lds[tid - d] : 0;
        __syncthreads();
        lds[tid] += add;
        __syncthreads();
    }
    int base = lds[tid] - inc;
#pragma unroll
    for (int i = 0; i < 16; ++i) {
        int e = base + run[i];
        off[tid * 16 + i] = e;
        cnt[tid * 16 + i] = e;   // cursor copy for scatter
    }
    if (tid == 1023) off[T_] = ET_;
}

__global__ void scatter_kernel(const int* __restrict__ eidx, int* __restrict__ cursor,
                               int* __restrict__ csr) {
    int j = blockIdx.x * 256 + threadIdx.x;
    if (j >= ET_) return;
    int s, d;
    decode_edge(j, eidx, eidx + E_, s, d);
    int pos = atomicAdd(&cursor[d], 1);
    csr[pos] = s;
}

// ---------------- layer 1 GEMM (K=10) + attn coeffs; h1 stored bf16 ---------
__global__ __launch_bounds__(256) void gemm1_kernel(
    const float* __restrict__ X, const float* __restrict__ W1,
    const float* __restrict__ a_s, const float* __restrict__ a_d,
    unsigned short* __restrict__ Hs, float* __restrict__ als,
    float* __restrict__ ald) {
    int tid = threadIdx.x, lane = tid & 63, wid = tid >> 6;
    int node = node_map(blockIdx.x, wid);
    int col = lane * 8;
    float x[F_];
    const float* xp = X + (size_t)node * F_;
#pragma unroll
    for (int k = 0; k < F_; ++k) x[k] = xp[k];
    f32x4 h0 = {0.f, 0.f, 0.f, 0.f}, h1 = h0;
#pragma unroll
    for (int k = 0; k < F_; ++k) {
        f32x4 w0 = *(const f32x4*)&W1[k * HC_ + col];
        f32x4 w1 = *(const f32x4*)&W1[k * HC_ + col + 4];
        h0 += x[k] * w0;
        h1 += x[k] * w1;
    }
    uint4 uh;
    uh.x = pack2(f2bf(h0[0]), f2bf(h0[1]));
    uh.y = pack2(f2bf(h0[2]), f2bf(h0[3]));
    uh.z = pack2(f2bf(h1[0]), f2bf(h1[1]));
    uh.w = pack2(f2bf(h1[2]), f2bf(h1[3]));
    *(uint4*)&Hs[(size_t)node * HC_ + col] = uh;
    // attention coeffs from full-precision registers
    float ps = dot4(h0, *(const f32x4*)&a_s[col]) + dot4(h1, *(const f32x4*)&a_s[col + 4]);
    float pd = dot4(h0, *(const f32x4*)&a_d[col]) + dot4(h1, *(const f32x4*)&a_d[col + 4]);
#pragma unroll
    for (int m = 1; m <= 16; m <<= 1) {
        ps += __shfl_xor(ps, m);
        pd += __shfl_xor(pd, m);
    }
    if (lane == 0)  { als[node * 2 + 0] = ps; ald[node * 2 + 0] = pd; }
    if (lane == 32) { als[node * 2 + 1] = ps; ald[node * 2 + 1] = pd; }
}

// ---------------- attn coeffs for layer 2 (from bf16 h2), wave/node ---------
__global__ __launch_bounds__(256) void al2_kernel(
    const unsigned short* __restrict__ Hs, const float* __restrict__ a_s,
    const float* __restrict__ a_d, float* __restrict__ als, float* __restrict__ ald) {
    int tid = threadIdx.x, lane = tid & 63, wid = tid >> 6;
    int node = node_map(blockIdx.x, wid);
    int col = lane * 8;
    uint4 hv = *(const uint4*)&Hs[(size_t)node * HC_ + col];
    float f[8];
    bf2x2(hv.x, f[0], f[1]); bf2x2(hv.y, f[2], f[3]);
    bf2x2(hv.z, f[4], f[5]); bf2x2(hv.w, f[6], f[7]);
    float ps = 0.f, pd = 0.f;
#pragma unroll
    for (int j = 0; j < 8; ++j) {
        ps = fmaf(f[j], a_s[col + j], ps);
        pd = fmaf(f[j], a_d[col + j], pd);
    }
#pragma unroll
    for (int m = 1; m <= 16; m <<= 1) {
        ps += __shfl_xor(ps, m);
        pd += __shfl_xor(pd, m);
    }
    if (lane == 0)  { als[node * 2 + 0] = ps; ald[node * 2 + 0] = pd; }
    if (lane == 32) { als[node * 2 + 1] = ps; ald[node * 2 + 1] = pd; }
}

// ---------------- GAT aggregation: wave per dst, bf16 h gather --------------
// MODE 0: output bf16 x1 (feeds MFMA gemm2). MODE 1: fused FC+BN+ReLU.
template <int MODE>
__global__ __launch_bounds__(256) void agg_kernel(
    const unsigned short* __restrict__ Hin, const float* __restrict__ als,
    const float* __restrict__ ald, const int* __restrict__ off,
    const int* __restrict__ csr, const float* __restrict__ bias,
    unsigned short* __restrict__ Ahi,
    const float* __restrict__ Wfc, const float* __restrict__ bfc,
    const float* __restrict__ gamma, const float* __restrict__ beta,
    float* __restrict__ out) {
    int tid = threadIdx.x, lane = tid & 63, wid = tid >> 6;
    int dst = node_map(blockIdx.x, wid);
    int beg = off[dst], end = off[dst + 1], deg = end - beg;
    float ad0 = ald[2 * dst], ad1 = ald[2 * dst + 1];
    int col = lane * 8;
    float A[8] = {0.f, 0.f, 0.f, 0.f, 0.f, 0.f, 0.f, 0.f};

    if (deg <= 64) {
        float e0 = -1e30f, e1 = -1e30f;
        int sl = 0;
        if (lane < deg) {
            sl = csr[beg + lane];
            float a0 = als[2 * sl], a1 = als[2 * sl + 1];
            e0 = a0 + ad0; e0 = e0 > 0.f ? e0 : 0.2f * e0;
            e1 = a1 + ad1; e1 = e1 > 0.f ? e1 : 0.2f * e1;
        }
        float m0 = e0, m1 = e1;
#pragma unroll
        for (int m = 1; m < 64; m <<= 1) {
            m0 = fmaxf(m0, __shfl_xor(m0, m));
            m1 = fmaxf(m1, __shfl_xor(m1, m));
        }
        float x0 = (lane < deg) ? expf(e0 - m0) : 0.f;
        float x1 = (lane < deg) ? expf(e1 - m1) : 0.f;
        float d0 = x0, d1 = x1;
#pragma unroll
        for (int m = 1; m < 64; m <<= 1) {
            d0 += __shfl_xor(d0, m);
            d1 += __shfl_xor(d1, m);
        }
        float w0l = x0 / (d0 + 1e-16f);
        float w1l = x1 / (d1 + 1e-16f);
        for (int e = 0; e < deg; ++e) {
            int s = __shfl(sl, e);
            // CONVERGENT shuffles (ternary around __shfl is UB under divergence)
            float wa = __shfl(w0l, e);
            float wb = __shfl(w1l, e);
            float w = (lane < 32) ? wa : wb;
            uint4 hv = *(const uint4*)(Hin + (size_t)s * HC_ + col);
            float f0, f1;
            bf2x2(hv.x, f0, f1); A[0] = fmaf(w, f0, A[0]); A[1] = fmaf(w, f1, A[1]);
            bf2x2(hv.y, f0, f1); A[2] = fmaf(w, f0, A[2]); A[3] = fmaf(w, f1, A[3]);
            bf2x2(hv.z, f0, f1); A[4] = fmaf(w, f0, A[4]); A[5] = fmaf(w, f1, A[5]);
            bf2x2(hv.w, f0, f1); A[6] = fmaf(w, f0, A[6]); A[7] = fmaf(w, f1, A[7]);
        }
    } else {
        float m0 = -1e30f, m1 = -1e30f;
        for (int k = beg + lane; k < end; k += 64) {
            int s = csr[k];
            float e0 = als[2 * s] + ad0; e0 = e0 > 0.f ? e0 : 0.2f * e0;
            float e1 = als[2 * s + 1] + ad1; e1 = e1 > 0.f ? e1 : 0.2f * e1;
            m0 = fmaxf(m0, e0);
            m1 = fmaxf(m1, e1);
        }
#pragma unroll
        for (int m = 1; m < 64; m <<= 1) {
            m0 = fmaxf(m0, __shfl_xor(m0, m));
            m1 = fmaxf(m1, __shfl_xor(m1, m));
        }
        float d0 = 0.f, d1 = 0.f;
        for (int k = beg + lane; k < end; k += 64) {
            int s = csr[k];
            float e0 = als[2 * s] + ad0; e0 = e0 > 0.f ? e0 : 0.2f * e0;
            float e1 = als[2 * s + 1] + ad1; e1 = e1 > 0.f ? e1 : 0.2f * e1;
            d0 += expf(e0 - m0);
            d1 += expf(e1 - m1);
        }
#pragma unroll
        for (int m = 1; m < 64; m <<= 1) {
            d0 += __shfl_xor(d0, m);
            d1 += __shfl_xor(d1, m);
        }
        float inv0 = 1.f / (d0 + 1e-16f);
        float inv1 = 1.f / (d1 + 1e-16f);
        for (int k = beg; k < end; ++k) {
            int s = csr[k];
            float e0 = als[2 * s] + ad0; e0 = e0 > 0.f ? e0 : 0.2f * e0;
            float e1 = als[2 * s + 1] + ad1; e1 = e1 > 0.f ? e1 : 0.2f * e1;
            float w0 = expf(e0 - m0) * inv0;
            float w1 = expf(e1 - m1) * inv1;
            float w = (lane < 32) ? w0 : w1;
            uint4 hv = *(const uint4*)(Hin + (size_t)s * HC_ + col);
            float f0, f1;
            bf2x2(hv.x, f0, f1); A[0] = fmaf(w, f0, A[0]); A[1] = fmaf(w, f1, A[1]);
            bf2x2(hv.y, f0, f1); A[2] = fmaf(w, f0, A[2]); A[3] = fmaf(w, f1, A[3]);
            bf2x2(hv.z, f0, f1); A[4] = fmaf(w, f0, A[4]); A[5] = fmaf(w, f1, A[5]);
            bf2x2(hv.w, f0, f1); A[6] = fmaf(w, f0, A[6]); A[7] = fmaf(w, f1, A[7]);
        }
    }

#pragma unroll
    for (int j = 0; j < 8; ++j) A[j] += bias[col + j];

    if (MODE == 0) {
        uint4 uh;
        uh.x = pack2(f2bf(A[0]), f2bf(A[1]));
        uh.y = pack2(f2bf(A[2]), f2bf(A[3]));
        uh.z = pack2(f2bf(A[4]), f2bf(A[5]));
        uh.w = pack2(f2bf(A[6]), f2bf(A[7]));
        *(uint4*)&Ahi[(size_t)dst * HC_ + col] = uh;
    } else {
        float y = 0.f;
#pragma unroll
        for (int j = 0; j < 8; ++j) y = fmaf(A[j], Wfc[col + j], y);
#pragma unroll
        for (int m = 1; m < 64; m <<= 1) y += __shfl_xor(y, m);
        if (lane == 0) {
            y += bfc[0];
            y = y * (gamma[0] * rsqrtf(1.f + 1e-5f)) + beta[0];
            out[dst] = y > 0.f ? y : 0.f;
        }
    }
}

// ---------------- W2 transpose + hi/lo bf16 split ----------------
__global__ __launch_bounds__(256) void wt_kernel(const float* __restrict__ W2,
                                                 unsigned short* __restrict__ Bhi,
                                                 unsigned short* __restrict__ Blo) {
    __shared__ float t[32][33];
    int tx = threadIdx.x & 31, ty = threadIdx.x >> 5;
    int kb = blockIdx.x * 32, nb = blockIdx.y * 32;
#pragma unroll
    for (int r = ty; r < 32; r += 8)
        t[r][tx] = W2[(size_t)(kb + r) * HC_ + nb + tx];
    __syncthreads();
#pragma unroll
    for (int r = ty; r < 32; r += 8) {
        float v = t[tx][r];
        unsigned short h = f2bf(v);
        Bhi[(size_t)(nb + r) * HC_ + kb + tx] = h;
        Blo[(size_t)(nb + r) * HC_ + kb + tx] = f2bf(v - __uint_as_float(((unsigned int)h) << 16));
    }
}

// ---------------- layer 2 GEMM: bf16x2 MFMA, 256x128 tile, bf16 out ---------
// global_load_lds staging (swizzle on SOURCE addr, linear LDS dest, XOR read),
// 2-deep async pipeline: raw s_barrier + explicit vmcnt, 1 barrier per K-step.
// Epilogue: LDS transpose (132-float padded rows) -> coalesced bf16 stores.
__global__ __launch_bounds__(512, 1) void gemm2_kernel(
    const unsigned short* __restrict__ Ahi,
    const unsigned short* __restrict__ Bhi, const unsigned short* __restrict__ Blo,
    unsigned short* __restrict__ H2) {
    // staging: per buf (64 KiB): A 256x64 @0, Bh 128x64 @32768, Bl 128x64 @49152
    // epilogue: 256 rows x 132 floats (528B rows) = 135168 B
    __shared__ __align__(16) char smem[135168];
    const int tid = threadIdx.x, lane = tid & 63, wid = tid >> 6;
    const int wr = wid >> 1, wc = wid & 1;
    const int g = (blockIdx.x & 7) * 32 + (blockIdx.x >> 3);  // XCD swizzle
    const int row0 = (g >> 2) * 256, col0 = (g & 3) * 128;
    const int lr = lane & 15, lk = lane >> 4;
    const int x7 = lr & 7;

    f32x4 acc[4][4] = {};

    const char* gsrc[8];
    int loff[8];
#pragma unroll
    for (int l = 0; l < 8; ++l) {
        int i = tid + l * 512;
        if (i < 2048) {
            int r = i >> 3, c = i & 7;
            gsrc[l] = (const char*)(Ahi + (size_t)(row0 + r) * HC_ + ((c ^ (r & 7)) << 3));
            loff[l] = i << 4;
        } else if (i < 3072) {
            int j = i - 2048, r = j >> 3, c = j & 7;
            gsrc[l] = (const char*)(Bhi + (size_t)(col0 + r) * HC_ + ((c ^ (r & 7)) << 3));
            loff[l] = 32768 + (j << 4);
        } else {
            int j = i - 3072, r = j >> 3, c = j & 7;
            gsrc[l] = (const char*)(Blo + (size_t)(col0 + r) * HC_ + ((c ^ (r & 7)) << 3));
            loff[l] = 49152 + (j << 4);
        }
    }
    char* lds0 = smem;

#pragma unroll
    for (int l = 0; l < 8; ++l) async_cp16(gsrc[l], lds0 + loff[l]);
    asm volatile("s_waitcnt vmcnt(0)" ::: "memory");
    __builtin_amdgcn_s_barrier();

    int cur = 0;
    for (int kt = 0; kt < 8; ++kt) {
        if (kt < 7) {
            char* dst = lds0 + ((cur ^ 1) << 16);
#pragma unroll
            for (int l = 0; l < 8; ++l)
                async_cp16(gsrc[l] + (size_t)(kt + 1) * 128, dst + loff[l]);
        }
        const char* base = lds0 + (cur << 16);
#pragma unroll
        for (int kk = 0; kk < 2; ++kk) {
            bf16x8 a[4], bh[4], bl[4];
            int cx = ((kk * 4 + lk) ^ x7) << 4;
#pragma unroll
            for (int m = 0; m < 4; ++m) {
                int ra = wr * 64 + m * 16 + lr;
                int rb = wc * 64 + m * 16 + lr;
                a[m]  = *(const bf16x8*)(base + ra * 128 + cx);
                bh[m] = *(const bf16x8*)(base + 32768 + rb * 128 + cx);
                bl[m] = *(const bf16x8*)(base + 49152 + rb * 128 + cx);
            }
#pragma unroll
            for (int m = 0; m < 4; ++m)
#pragma unroll
                for (int n = 0; n < 4; ++n) {
                    acc[m][n] = __builtin_amdgcn_mfma_f32_16x16x32_bf16(a[m], bh[n], acc[m][n], 0, 0, 0);
                    acc[m][n] = __builtin_amdgcn_mfma_f32_16x16x32_bf16(a[m], bl[n], acc[m][n], 0, 0, 0);
                }
        }
        asm volatile("s_waitcnt vmcnt(0)" ::: "memory");
        __builtin_amdgcn_s_barrier();
        cur ^= 1;
    }

    // epilogue: acc -> LDS (padded) -> coalesced bf16 global stores
    float* tb = (float*)smem;
#pragma unroll
    for (int m = 0; m < 4; ++m)
#pragma unroll
        for (int i = 0; i < 4; ++i) {
            int row = wr * 64 + m * 16 + lk * 4 + i;
#pragma unroll
            for (int n = 0; n < 4; ++n)
                tb[row * 132 + wc * 64 + n * 16 + lr] = acc[m][n][i];
        }
    __syncthreads();
#pragma unroll
    for (int p = 0; p < 8; ++p) {
        int q = tid + p * 512;
        int row = q >> 4, cs = (q & 15) * 8;
        const float* v = &tb[row * 132 + cs];
        uint4 uh;
        uh.x = pack2(f2bf(v[0]), f2bf(v[1]));
        uh.y = pack2(f2bf(v[2]), f2bf(v[3]));
        uh.z = pack2(f2bf(v[4]), f2bf(v[5]));
        uh.w = pack2(f2bf(v[6]), f2bf(v[7]));
        *(uint4*)&H2[(size_t)(row0 + row) * HC_ + col0 + cs] = uh;
    }
}

// ---------------- launcher ----------------
extern "C" void kernel_launch(void* const* d_in, const int* in_sizes, int n_in,
                              void* d_out, int out_size, void* d_ws, size_t ws_size,
                              hipStream_t stream) {
    const float* data  = (const float*)d_in[0];
    const int*   eidx  = (const int*)d_in[1];
    const float* W1    = (const float*)d_in[2];
    const float* as1   = (const float*)d_in[3];
    const float* ad1   = (const float*)d_in[4];
    const float* b1    = (const float*)d_in[5];
    const float* W2    = (const float*)d_in[6];
    const float* as2   = (const float*)d_in[7];
    const float* ad2   = (const float*)d_in[8];
    const float* b2    = (const float*)d_in[9];
    const float* Wfc   = (const float*)d_in[10];
    const float* bfc   = (const float*)d_in[11];
    const float* gamma = (const float*)d_in[12];
    const float* beta  = (const float*)d_in[13];
    float* out = (float*)d_out;

    char* base = (char*)d_ws;
    size_t o = 0;
    auto take = [&](size_t bytes) {
        char* p = base + o;
        o = (o + bytes + 255) & ~(size_t)255;
        return p;
    };
    int*   cnt  = (int*)take((size_t)T_ * 4);
    int*   off  = (int*)take((size_t)(T_ + 1) * 4);
    int*   csr  = (int*)take((size_t)ET_ * 4);
    float* als1 = (float*)take((size_t)T_ * 2 * 4);
    float* ald1 = (float*)take((size_t)T_ * 2 * 4);
    float* als2 = (float*)take((size_t)T_ * 2 * 4);
    float* ald2 = (float*)take((size_t)T_ * 2 * 4);
    unsigned short* hs1 = (unsigned short*)take((size_t)T_ * HC_ * 2);  // h1 bf16
    unsigned short* hs2 = (unsigned short*)take((size_t)T_ * HC_ * 2);  // h2 bf16
    unsigned short* Ahi = (unsigned short*)take((size_t)T_ * HC_ * 2);  // x1 bf16
    unsigned short* Bhi = (unsigned short*)take((size_t)HC_ * HC_ * 2);
    unsigned short* Blo = (unsigned short*)take((size_t)HC_ * HC_ * 2);
    // total ~51 MiB (< R1's proven 65.7 MiB)

    const int egrid = (ET_ + 255) / 256;

    hipMemsetAsync(cnt, 0, (size_t)T_ * 4, stream);
    hist_kernel<<<egrid, 256, 0, stream>>>(eidx, cnt);
    scan_kernel<<<1, 1024, 0, stream>>>(cnt, off);
    scatter_kernel<<<egrid, 256, 0, stream>>>(eidx, cnt, csr);
    wt_kernel<<<dim3(16, 16), 256, 0, stream>>>(W2, Bhi, Blo);

    gemm1_kernel<<<4096, 256, 0, stream>>>(data, W1, as1, ad1, hs1, als1, ald1);
    agg_kernel<0><<<4096, 256, 0, stream>>>(hs1, als1, ald1, off, csr, b1,
                                            Ahi, nullptr, nullptr, nullptr,
                                            nullptr, nullptr);
    gemm2_kernel<<<256, 512, 0, stream>>>(Ahi, Bhi, Blo, hs2);
    al2_kernel<<<4096, 256, 0, stream>>>(hs2, as2, ad2, als2, ald2);
    agg_kernel<1><<<4096, 256, 0, stream>>>(hs2, als2, ald2, off, csr, b2,
                                            nullptr, Wfc, bfc, gamma,
                                            beta, out);
}

// Round 8
// 99.880 us; speedup vs baseline: 3.8907x; 1.2094x over previous
//
#include <hip/hip_runtime.h>
#include <math.h>

#define B_  32
#define F_  10
#define N_  512
#define E_  8192
#define T_  16384      /* B_*N_ total nodes */
#define EC_ 8704       /* per-batch edges incl self-loops: E_+N_ */
#define HC_ 512
#define C_  256

typedef __attribute__((ext_vector_type(8))) short bf16x8;
typedef __attribute__((ext_vector_type(4))) float f32x4;

__device__ __forceinline__ unsigned short f2bf(float f) {
    unsigned int u = __float_as_uint(f);
    u = (u + 0x7fffu + ((u >> 16) & 1u)) >> 16;
    return (unsigned short)u;
}
__device__ __forceinline__ float bf2f(unsigned short b) {
    return __uint_as_float(((unsigned int)b) << 16);
}
__device__ __forceinline__ float dot4(f32x4 a, f32x4 b) {
    f32x4 m = a * b;
    return m[0] + m[1] + m[2] + m[3];
}
__device__ __forceinline__ unsigned int pack2(unsigned short a, unsigned short b) {
    return (unsigned int)a | ((unsigned int)b << 16);
}
// expand packed 2x bf16 -> 2 floats
__device__ __forceinline__ void bf2x2(unsigned int u, float& f0, float& f1) {
    f0 = __uint_as_float(u << 16);
    f1 = __uint_as_float(u & 0xffff0000u);
}
__device__ __forceinline__ void async_cp16(const void* g, void* l) {
    __builtin_amdgcn_global_load_lds(
        (const __attribute__((address_space(1))) unsigned int*)g,
        (__attribute__((address_space(3))) unsigned int*)l, 16, 0, 0);
}

// batch→XCD swizzle
__device__ __forceinline__ int node_map(int bid, int wid) {
    int x = bid & 7;
    int rest = bid >> 3;          // 0..511
    int batch = x * 4 + (rest >> 7);
    int within = rest & 127;
    return batch * 512 + within * 4 + wid;
}

// ---------------- prep: W2 transpose+split (blocks 0..255) + per-batch CSR (block 256)
__global__ __launch_bounds__(1024) void prep_kernel(
    const int* __restrict__ eidx, const float* __restrict__ W2,
    int* __restrict__ off0, int* __restrict__ csr0,
    unsigned short* __restrict__ Bhi, unsigned short* __restrict__ Blo) {
    if (blockIdx.x < 256) {
        __shared__ float t[32][33];
        int bx = blockIdx.x & 15, by = blockIdx.x >> 4;
        int kb = bx * 32, nb = by * 32;
        int tx = threadIdx.x & 31, r = threadIdx.x >> 5;
        t[r][tx] = W2[(size_t)(kb + r) * HC_ + nb + tx];
        __syncthreads();
        float v = t[tx][r];
        unsigned short h = f2bf(v);
        Bhi[(size_t)(nb + r) * HC_ + kb + tx] = h;
        Blo[(size_t)(nb + r) * HC_ + kb + tx] = f2bf(v - bf2f(h));
    } else {
        // CSR for the batch-0 graph: 512 nodes, 8704 edges (8192 + self-loops)
        __shared__ int cnt[512];
        __shared__ int scn[512];
        int tid = threadIdx.x;
        if (tid < 512) cnt[tid] = 0;
        __syncthreads();
        const int* edst = eidx + E_;
        for (int j = tid; j < EC_; j += 1024) {
            int d = (j < E_) ? edst[j] : (j - E_);
            atomicAdd(&cnt[d], 1);
        }
        __syncthreads();
        if (tid < 512) scn[tid] = cnt[tid];
        __syncthreads();
        for (int dd = 1; dd < 512; dd <<= 1) {
            int add = (tid < 512 && tid >= dd) ? scn[tid - dd] : 0;
            __syncthreads();
            if (tid < 512) scn[tid] += add;
            __syncthreads();
        }
        if (tid < 512) {
            int excl = scn[tid] - cnt[tid];
            off0[tid] = excl;
            cnt[tid] = excl;            // cursor
        }
        if (tid == 0) off0[512] = EC_;
        __syncthreads();
        for (int j = tid; j < EC_; j += 1024) {
            int s, d;
            if (j < E_) { s = eidx[j]; d = edst[j]; }
            else { s = d = j - E_; }
            int pos = atomicAdd(&cnt[d], 1);
            csr0[pos] = s;
        }
    }
}

// ---------------- layer 1 GEMM (K=10) + attn coeffs; h1 bf16; zero als2/ald2
__global__ __launch_bounds__(256) void gemm1_kernel(
    const float* __restrict__ X, const float* __restrict__ W1,
    const float* __restrict__ a_s, const float* __restrict__ a_d,
    unsigned short* __restrict__ Hs, float* __restrict__ als,
    float* __restrict__ ald, float* __restrict__ als2z,
    float* __restrict__ ald2z) {
    int tid = threadIdx.x, lane = tid & 63, wid = tid >> 6;
    int node = node_map(blockIdx.x, wid);
    int col = lane * 8;
    float x[F_];
    const float* xp = X + (size_t)node * F_;
#pragma unroll
    for (int k = 0; k < F_; ++k) x[k] = xp[k];
    f32x4 h0 = {0.f, 0.f, 0.f, 0.f}, h1 = h0;
#pragma unroll
    for (int k = 0; k < F_; ++k) {
        f32x4 w0 = *(const f32x4*)&W1[k * HC_ + col];
        f32x4 w1 = *(const f32x4*)&W1[k * HC_ + col + 4];
        h0 += x[k] * w0;
        h1 += x[k] * w1;
    }
    uint4 uh;
    uh.x = pack2(f2bf(h0[0]), f2bf(h0[1]));
    uh.y = pack2(f2bf(h0[2]), f2bf(h0[3]));
    uh.z = pack2(f2bf(h1[0]), f2bf(h1[1]));
    uh.w = pack2(f2bf(h1[2]), f2bf(h1[3]));
    *(uint4*)&Hs[(size_t)node * HC_ + col] = uh;
    float ps = dot4(h0, *(const f32x4*)&a_s[col]) + dot4(h1, *(const f32x4*)&a_s[col + 4]);
    float pd = dot4(h0, *(const f32x4*)&a_d[col]) + dot4(h1, *(const f32x4*)&a_d[col + 4]);
#pragma unroll
    for (int m = 1; m <= 16; m <<= 1) {
        ps += __shfl_xor(ps, m);
        pd += __shfl_xor(pd, m);
    }
    if (lane == 0)  { als[node * 2 + 0] = ps; ald[node * 2 + 0] = pd; }
    if (lane == 32) { als[node * 2 + 1] = ps; ald[node * 2 + 1] = pd; }
    if (lane == 16) {   // zero layer-2 coeff accumulators (filled by gemm2 atomics)
        *(float2*)&als2z[node * 2] = make_float2(0.f, 0.f);
        *(float2*)&ald2z[node * 2] = make_float2(0.f, 0.f);
    }
}

// ---------------- GAT aggregation: wave per dst, per-batch CSR --------------
// MODE 0: output bf16 x1 (feeds MFMA gemm2). MODE 1: fused FC+BN+ReLU.
template <int MODE>
__global__ __launch_bounds__(256) void agg_kernel(
    const unsigned short* __restrict__ Hin, const float* __restrict__ als,
    const float* __restrict__ ald, const int* __restrict__ off0,
    const int* __restrict__ csr0, const float* __restrict__ bias,
    unsigned short* __restrict__ Ahi,
    const float* __restrict__ Wfc, const float* __restrict__ bfc,
    const float* __restrict__ gamma, const float* __restrict__ beta,
    float* __restrict__ out) {
    int tid = threadIdx.x, lane = tid & 63, wid = tid >> 6;
    int dst = node_map(blockIdx.x, wid);
    int bbase = dst & ~511;          // batch * 512
    int dl = dst & 511;              // local node id
    int beg = off0[dl], end = off0[dl + 1], deg = end - beg;
    float ad0 = ald[2 * dst], ad1 = ald[2 * dst + 1];
    int col = lane * 8;
    float A[8] = {0.f, 0.f, 0.f, 0.f, 0.f, 0.f, 0.f, 0.f};

    if (deg <= 64) {
        float e0 = -1e30f, e1 = -1e30f;
        int sl = 0;
        if (lane < deg) {
            sl = csr0[beg + lane] + bbase;
            float a0 = als[2 * sl], a1 = als[2 * sl + 1];
            e0 = a0 + ad0; e0 = e0 > 0.f ? e0 : 0.2f * e0;
            e1 = a1 + ad1; e1 = e1 > 0.f ? e1 : 0.2f * e1;
        }
        float m0 = e0, m1 = e1;
#pragma unroll
        for (int m = 1; m < 64; m <<= 1) {
            m0 = fmaxf(m0, __shfl_xor(m0, m));
            m1 = fmaxf(m1, __shfl_xor(m1, m));
        }
        float x0 = (lane < deg) ? expf(e0 - m0) : 0.f;
        float x1 = (lane < deg) ? expf(e1 - m1) : 0.f;
        float d0 = x0, d1 = x1;
#pragma unroll
        for (int m = 1; m < 64; m <<= 1) {
            d0 += __shfl_xor(d0, m);
            d1 += __shfl_xor(d1, m);
        }
        float w0l = x0 / (d0 + 1e-16f);
        float w1l = x1 / (d1 + 1e-16f);
        for (int e = 0; e < deg; ++e) {
            int s = __shfl(sl, e);
            // CONVERGENT shuffles (ternary around __shfl is UB under divergence)
            float wa = __shfl(w0l, e);
            float wb = __shfl(w1l, e);
            float w = (lane < 32) ? wa : wb;
            uint4 hv = *(const uint4*)(Hin + (size_t)s * HC_ + col);
            float f0, f1;
            bf2x2(hv.x, f0, f1); A[0] = fmaf(w, f0, A[0]); A[1] = fmaf(w, f1, A[1]);
            bf2x2(hv.y, f0, f1); A[2] = fmaf(w, f0, A[2]); A[3] = fmaf(w, f1, A[3]);
            bf2x2(hv.z, f0, f1); A[4] = fmaf(w, f0, A[4]); A[5] = fmaf(w, f1, A[5]);
            bf2x2(hv.w, f0, f1); A[6] = fmaf(w, f0, A[6]); A[7] = fmaf(w, f1, A[7]);
        }
    } else {
        float m0 = -1e30f, m1 = -1e30f;
        for (int k = beg + lane; k < end; k += 64) {
            int s = csr0[k] + bbase;
            float e0 = als[2 * s] + ad0; e0 = e0 > 0.f ? e0 : 0.2f * e0;
            float e1 = als[2 * s + 1] + ad1; e1 = e1 > 0.f ? e1 : 0.2f * e1;
            m0 = fmaxf(m0, e0);
            m1 = fmaxf(m1, e1);
        }
#pragma unroll
        for (int m = 1; m < 64; m <<= 1) {
            m0 = fmaxf(m0, __shfl_xor(m0, m));
            m1 = fmaxf(m1, __shfl_xor(m1, m));
        }
        float d0 = 0.f, d1 = 0.f;
        for (int k = beg + lane; k < end; k += 64) {
            int s = csr0[k] + bbase;
            float e0 = als[2 * s] + ad0; e0 = e0 > 0.f ? e0 : 0.2f * e0;
            float e1 = als[2 * s + 1] + ad1; e1 = e1 > 0.f ? e1 : 0.2f * e1;
            d0 += expf(e0 - m0);
            d1 += expf(e1 - m1);
        }
#pragma unroll
        for (int m = 1; m < 64; m <<= 1) {
            d0 += __shfl_xor(d0, m);
            d1 += __shfl_xor(d1, m);
        }
        float inv0 = 1.f / (d0 + 1e-16f);
        float inv1 = 1.f / (d1 + 1e-16f);
        for (int k = beg; k < end; ++k) {
            int s = csr0[k] + bbase;
            float e0 = als[2 * s] + ad0; e0 = e0 > 0.f ? e0 : 0.2f * e0;
            float e1 = als[2 * s + 1] + ad1; e1 = e1 > 0.f ? e1 : 0.2f * e1;
            float w0 = expf(e0 - m0) * inv0;
            float w1 = expf(e1 - m1) * inv1;
            float w = (lane < 32) ? w0 : w1;
            uint4 hv = *(const uint4*)(Hin + (size_t)s * HC_ + col);
            float f0, f1;
            bf2x2(hv.x, f0, f1); A[0] = fmaf(w, f0, A[0]); A[1] = fmaf(w, f1, A[1]);
            bf2x2(hv.y, f0, f1); A[2] = fmaf(w, f0, A[2]); A[3] = fmaf(w, f1, A[3]);
            bf2x2(hv.z, f0, f1); A[4] = fmaf(w, f0, A[4]); A[5] = fmaf(w, f1, A[5]);
            bf2x2(hv.w, f0, f1); A[6] = fmaf(w, f0, A[6]); A[7] = fmaf(w, f1, A[7]);
        }
    }

#pragma unroll
    for (int j = 0; j < 8; ++j) A[j] += bias[col + j];

    if (MODE == 0) {
        uint4 uh;
        uh.x = pack2(f2bf(A[0]), f2bf(A[1]));
        uh.y = pack2(f2bf(A[2]), f2bf(A[3]));
        uh.z = pack2(f2bf(A[4]), f2bf(A[5]));
        uh.w = pack2(f2bf(A[6]), f2bf(A[7]));
        *(uint4*)&Ahi[(size_t)dst * HC_ + col] = uh;
    } else {
        float y = 0.f;
#pragma unroll
        for (int j = 0; j < 8; ++j) y = fmaf(A[j], Wfc[col + j], y);
#pragma unroll
        for (int m = 1; m < 64; m <<= 1) y += __shfl_xor(y, m);
        if (lane == 0) {
            y += bfc[0];
            y = y * (gamma[0] * rsqrtf(1.f + 1e-5f)) + beta[0];
            out[dst] = y > 0.f ? y : 0.f;
        }
    }
}

// ---------------- layer 2 GEMM: bf16x2 MFMA, 256x128 tile, bf16 out ---------
// + FUSED al2: partial dots with as2/ad2 from the LDS epilogue tile,
//   16-lane shuffle reduce, atomicAdd into als2/ald2 (zeroed by gemm1).
__global__ __launch_bounds__(512, 1) void gemm2_kernel(
    const unsigned short* __restrict__ Ahi,
    const unsigned short* __restrict__ Bhi, const unsigned short* __restrict__ Blo,
    unsigned short* __restrict__ H2,
    const float* __restrict__ as2, const float* __restrict__ ad2,
    float* __restrict__ als2, float* __restrict__ ald2) {
    __shared__ __align__(16) char smem[135168];
    const int tid = threadIdx.x, lane = tid & 63, wid = tid >> 6;
    const int wr = wid >> 1, wc = wid & 1;
    const int g = (blockIdx.x & 7) * 32 + (blockIdx.x >> 3);  // XCD swizzle
    const int row0 = (g >> 2) * 256, col0 = (g & 3) * 128;
    const int lr = lane & 15, lk = lane >> 4;
    const int x7 = lr & 7;

    f32x4 acc[4][4] = {};

    const char* gsrc[8];
    int loff[8];
#pragma unroll
    for (int l = 0; l < 8; ++l) {
        int i = tid + l * 512;
        if (i < 2048) {
            int r = i >> 3, c = i & 7;
            gsrc[l] = (const char*)(Ahi + (size_t)(row0 + r) * HC_ + ((c ^ (r & 7)) << 3));
            loff[l] = i << 4;
        } else if (i < 3072) {
            int j = i - 2048, r = j >> 3, c = j & 7;
            gsrc[l] = (const char*)(Bhi + (size_t)(col0 + r) * HC_ + ((c ^ (r & 7)) << 3));
            loff[l] = 32768 + (j << 4);
        } else {
            int j = i - 3072, r = j >> 3, c = j & 7;
            gsrc[l] = (const char*)(Blo + (size_t)(col0 + r) * HC_ + ((c ^ (r & 7)) << 3));
            loff[l] = 49152 + (j << 4);
        }
    }
    char* lds0 = smem;

#pragma unroll
    for (int l = 0; l < 8; ++l) async_cp16(gsrc[l], lds0 + loff[l]);
    asm volatile("s_waitcnt vmcnt(0)" ::: "memory");
    __builtin_amdgcn_s_barrier();

    int cur = 0;
    for (int kt = 0; kt < 8; ++kt) {
        if (kt < 7) {
            char* dst = lds0 + ((cur ^ 1) << 16);
#pragma unroll
            for (int l = 0; l < 8; ++l)
                async_cp16(gsrc[l] + (size_t)(kt + 1) * 128, dst + loff[l]);
        }
        const char* base = lds0 + (cur << 16);
#pragma unroll
        for (int kk = 0; kk < 2; ++kk) {
            bf16x8 a[4], bh[4], bl[4];
            int cx = ((kk * 4 + lk) ^ x7) << 4;
#pragma unroll
            for (int m = 0; m < 4; ++m) {
                int ra = wr * 64 + m * 16 + lr;
                int rb = wc * 64 + m * 16 + lr;
                a[m]  = *(const bf16x8*)(base + ra * 128 + cx);
                bh[m] = *(const bf16x8*)(base + 32768 + rb * 128 + cx);
                bl[m] = *(const bf16x8*)(base + 49152 + rb * 128 + cx);
            }
#pragma unroll
            for (int m = 0; m < 4; ++m)
#pragma unroll
                for (int n = 0; n < 4; ++n) {
                    acc[m][n] = __builtin_amdgcn_mfma_f32_16x16x32_bf16(a[m], bh[n], acc[m][n], 0, 0, 0);
                    acc[m][n] = __builtin_amdgcn_mfma_f32_16x16x32_bf16(a[m], bl[n], acc[m][n], 0, 0, 0);
                }
        }
        asm volatile("s_waitcnt vmcnt(0)" ::: "memory");
        __builtin_amdgcn_s_barrier();
        cur ^= 1;
    }

    // epilogue: acc -> LDS (padded) -> coalesced bf16 stores + fused al2
    float* tb = (float*)smem;
#pragma unroll
    for (int m = 0; m < 4; ++m)
#pragma unroll
        for (int i = 0; i < 4; ++i) {
            int row = wr * 64 + m * 16 + lk * 4 + i;
#pragma unroll
            for (int n = 0; n < 4; ++n)
                tb[row * 132 + wc * 64 + n * 16 + lr] = acc[m][n][i];
        }
    __syncthreads();
    const int head = col0 >> 8;                    // this block's 128 cols lie in one head
    const float* a_s2 = as2 + head * C_ + (col0 & 255);
    const float* a_d2 = ad2 + head * C_ + (col0 & 255);
#pragma unroll
    for (int p = 0; p < 8; ++p) {
        int q = tid + p * 512;
        int row = q >> 4, cs = (q & 15) * 8;
        const float* v = &tb[row * 132 + cs];
        uint4 uh;
        uh.x = pack2(f2bf(v[0]), f2bf(v[1]));
        uh.y = pack2(f2bf(v[2]), f2bf(v[3]));
        uh.z = pack2(f2bf(v[4]), f2bf(v[5]));
        uh.w = pack2(f2bf(v[6]), f2bf(v[7]));
        *(uint4*)&H2[(size_t)(row0 + row) * HC_ + col0 + cs] = uh;
        float ps = 0.f, pd = 0.f;
#pragma unroll
        for (int j = 0; j < 8; ++j) {
            ps = fmaf(v[j], a_s2[cs + j], ps);
            pd = fmaf(v[j], a_d2[cs + j], pd);
        }
#pragma unroll
        for (int m = 1; m < 16; m <<= 1) {   // reduce across the 16 lanes of one row
            ps += __shfl_xor(ps, m);
            pd += __shfl_xor(pd, m);
        }
        if ((tid & 15) == 0) {
            atomicAdd(&als2[(row0 + row) * 2 + head], ps);
            atomicAdd(&ald2[(row0 + row) * 2 + head], pd);
        }
    }
}

// ---------------- launcher ----------------
extern "C" void kernel_launch(void* const* d_in, const int* in_sizes, int n_in,
                              void* d_out, int out_size, void* d_ws, size_t ws_size,
                              hipStream_t stream) {
    const float* data  = (const float*)d_in[0];
    const int*   eidx  = (const int*)d_in[1];
    const float* W1    = (const float*)d_in[2];
    const float* as1   = (const float*)d_in[3];
    const float* ad1   = (const float*)d_in[4];
    const float* b1    = (const float*)d_in[5];
    const float* W2    = (const float*)d_in[6];
    const float* as2   = (const float*)d_in[7];
    const float* ad2   = (const float*)d_in[8];
    const float* b2    = (const float*)d_in[9];
    const float* Wfc   = (const float*)d_in[10];
    const float* bfc   = (const float*)d_in[11];
    const float* gamma = (const float*)d_in[12];
    const float* beta  = (const float*)d_in[13];
    float* out = (float*)d_out;

    char* base = (char*)d_ws;
    size_t o = 0;
    auto take = [&](size_t bytes) {
        char* p = base + o;
        o = (o + bytes + 255) & ~(size_t)255;
        return p;
    };
    int*   off0 = (int*)take((size_t)(N_ + 1) * 4);
    int*   csr0 = (int*)take((size_t)EC_ * 4);
    float* als1 = (float*)take((size_t)T_ * 2 * 4);
    float* ald1 = (float*)take((size_t)T_ * 2 * 4);
    float* als2 = (float*)take((size_t)T_ * 2 * 4);
    float* ald2 = (float*)take((size_t)T_ * 2 * 4);
    unsigned short* hs1 = (unsigned short*)take((size_t)T_ * HC_ * 2);  // h1 bf16
    unsigned short* hs2 = (unsigned short*)take((size_t)T_ * HC_ * 2);  // h2 bf16
    unsigned short* Ahi = (unsigned short*)take((size_t)T_ * HC_ * 2);  // x1 bf16
    unsigned short* Bhi = (unsigned short*)take((size_t)HC_ * HC_ * 2);
    unsigned short* Blo = (unsigned short*)take((size_t)HC_ * HC_ * 2);

    prep_kernel<<<257, 1024, 0, stream>>>(eidx, W2, off0, csr0, Bhi, Blo);
    gemm1_kernel<<<4096, 256, 0, stream>>>(data, W1, as1, ad1, hs1, als1, ald1,
                                           als2, ald2);
    agg_kernel<0><<<4096, 256, 0, stream>>>(hs1, als1, ald1, off0, csr0, b1,
                                            Ahi, nullptr, nullptr, nullptr,
                                            nullptr, nullptr);
    gemm2_kernel<<<256, 512, 0, stream>>>(Ahi, Bhi, Blo, hs2, as2, ad2, als2, ald2);
    agg_kernel<1><<<4096, 256, 0, stream>>>(hs2, als2, ald2, off0, csr0, b2,
                                            nullptr, Wfc, bfc, gamma,
                                            beta, out);
}